// Round 9
// baseline (468.752 us; speedup 1.0000x reference)
//
#include <hip/hip_runtime.h>
#include <math.h>

#define NN 30000
#define EE 480000
#define DIM 128
#define KVB 512   // kv_part blocks

typedef __attribute__((ext_vector_type(8))) short bf16x8;
typedef __attribute__((ext_vector_type(8))) short s16x8;
typedef __attribute__((ext_vector_type(4))) short s16x4;
typedef __attribute__((ext_vector_type(4))) float f32x4;
typedef __attribute__((ext_vector_type(4))) float float4v;
typedef unsigned short ushort_t;

__device__ inline short f2bf(float f) {      // RNE f32 -> bf16
    union { float f; unsigned u; } v; v.f = f;
    unsigned u = v.u;
    u += 0x7fffu + ((u >> 16) & 1u);
    return (short)(u >> 16);
}
__device__ inline float bf2f(unsigned short u) {
    union { unsigned u; float f; } v; v.u = ((unsigned)u) << 16; return v.f;
}
__device__ inline unsigned pack2(float a, float b) {
    return (unsigned)(ushort_t)f2bf(a) | ((unsigned)(ushort_t)f2bf(b) << 16);
}

__device__ inline bf16x8 cvt8(float4v lo, float4v hi) {
    bf16x8 r;
    r[0] = f2bf(lo[0]); r[1] = f2bf(lo[1]); r[2] = f2bf(lo[2]); r[3] = f2bf(lo[3]);
    r[4] = f2bf(hi[0]); r[5] = f2bf(hi[1]); r[6] = f2bf(hi[2]); r[7] = f2bf(hi[3]);
    return r;
}
__device__ inline void bf8_to_f(bf16x8 v, float4v& lo, float4v& hi) {
#pragma unroll
    for (int i = 0; i < 4; ++i) {
        lo[i] = bf2f((unsigned short)v[i]);
        hi[i] = bf2f((unsigned short)v[4 + i]);
    }
}

// ---------------- weight pre-pack (fragment-major bf16) ----------------
__global__ void pack_all(const float* __restrict__ fc1, const float* __restrict__ fcv,
                         const float* __restrict__ wout, const float* __restrict__ wvp,
                         const float* __restrict__ fco, const float* __restrict__ weq,
                         short* __restrict__ Wpk) {
    int fid = blockIdx.x * 4 + (threadIdx.x >> 6);
    int lane = threadIdx.x & 63;
    const float* src; int Nsrc, c0, f;
    if (fid < 96)       { src = fc1;  Nsrc = 384; c0 = 0;   f = fid; }
    else if (fid < 192) { src = fcv;  Nsrc = 384; c0 = 0;   f = fid - 96; }
    else if (fid < 288) { src = wout; Nsrc = 384; c0 = 0;   f = fid - 192; }
    else if (fid < 352) { src = wvp;  Nsrc = 384; c0 = 0;   f = fid - 288; }
    else if (fid < 384) { src = wvp;  Nsrc = 384; c0 = 256; f = fid - 352; }
    else if (fid < 416) { src = fco;  Nsrc = 128; c0 = 0;   f = fid - 384; }
    else                { src = weq;  Nsrc = 128; c0 = 0;   f = fid - 416; }
    int ct = f >> 2, kk = f & 3;
    int k0 = kk * 32 + (lane >> 4) * 8;
    int col = c0 + ct * 16 + (lane & 15);
    bf16x8 v;
#pragma unroll
    for (int i = 0; i < 8; ++i) v[i] = f2bf(src[(size_t)(k0 + i) * Nsrc + col]);
    *(bf16x8*)(Wpk + ((size_t)fid * 64 + lane) * 8) = v;
}

// ---------------- generic MFMA GEMM with col-tile blocking (blockIdx.y) -------------------
template<int COLS, int CT_PER, bool BIAS, typename InT, typename OutT>
__global__ __launch_bounds__(256) void mfma_gemm(const InT* __restrict__ in,
        const short* __restrict__ Wpk, const float* __restrict__ bias,
        OutT* __restrict__ out, int nrows) {
    const int lane = threadIdx.x & 63;
    const int wid = threadIdx.x >> 6;
    const int rbase = blockIdx.x * 128 + wid * 32;
    if (rbase >= nrows) return;
    const int ct0 = blockIdx.y * CT_PER;
    const int rlo = lane & 15, khi = (lane >> 4) * 8;
    bf16x8 a[2][4];
#pragma unroll
    for (int t = 0; t < 2; ++t) {
        int row = min(rbase + t * 16 + rlo, nrows - 1);
        const InT* rp = in + (size_t)row * 128 + khi;
#pragma unroll
        for (int kk = 0; kk < 4; ++kk) {
            if constexpr (sizeof(InT) == 4) {
                float4v lo = *(const float4v*)(rp + kk * 32);
                float4v hi = *(const float4v*)(rp + kk * 32 + 4);
                a[t][kk] = cvt8(lo, hi);
            } else {
                a[t][kk] = *(const bf16x8*)(rp + kk * 32);
            }
        }
    }
#pragma unroll
    for (int c = 0; c < CT_PER; ++c) {
        const int ct = ct0 + c;
        bf16x8 b[4];
#pragma unroll
        for (int kk = 0; kk < 4; ++kk)
            b[kk] = *(const bf16x8*)(Wpk + ((size_t)(ct * 4 + kk) * 64 + lane) * 8);
        f32x4 acc0 = {0.f, 0.f, 0.f, 0.f}, acc1 = {0.f, 0.f, 0.f, 0.f};
#pragma unroll
        for (int kk = 0; kk < 4; ++kk) {
            acc0 = __builtin_amdgcn_mfma_f32_16x16x32_bf16(a[0][kk], b[kk], acc0, 0, 0, 0);
            acc1 = __builtin_amdgcn_mfma_f32_16x16x32_bf16(a[1][kk], b[kk], acc1, 0, 0, 0);
        }
        const int col = ct * 16 + rlo;
        const float bv = BIAS ? bias[col] : 0.f;
#pragma unroll
        for (int r = 0; r < 4; ++r) {
            int row0 = rbase + (lane >> 4) * 4 + r;
            int row1 = row0 + 16;
            if constexpr (sizeof(OutT) == 4) {
                if (row0 < nrows) out[(size_t)row0 * COLS + col] = acc0[r] + bv;
                if (row1 < nrows) out[(size_t)row1 * COLS + col] = acc1[r] + bv;
            } else {
                if (row0 < nrows) out[(size_t)row0 * COLS + col] = (OutT)f2bf(acc0[r] + bv);
                if (row1 < nrows) out[(size_t)row1 * COLS + col] = (OutT)f2bf(acc1[r] + bv);
            }
        }
    }
}

// ---------------- vecproj GEMM (384 cols): cols<256 -> vp12 bf16, cols>=256 -> v3p bf16 ---
__global__ __launch_bounds__(256) void vp_gemm(const float* __restrict__ in,
        const short* __restrict__ Wpk, ushort_t* __restrict__ vp12,
        ushort_t* __restrict__ v3p, int nrows) {
    const int lane = threadIdx.x & 63;
    const int wid = threadIdx.x >> 6;
    const int rbase = blockIdx.x * 128 + wid * 32;
    if (rbase >= nrows) return;
    const int ct0 = blockIdx.y * 8;
    const int rlo = lane & 15, khi = (lane >> 4) * 8;
    bf16x8 a[2][4];
#pragma unroll
    for (int t = 0; t < 2; ++t) {
        int row = min(rbase + t * 16 + rlo, nrows - 1);
        const float* rp = in + (size_t)row * 128 + khi;
#pragma unroll
        for (int kk = 0; kk < 4; ++kk) {
            float4v lo = *(const float4v*)(rp + kk * 32);
            float4v hi = *(const float4v*)(rp + kk * 32 + 4);
            a[t][kk] = cvt8(lo, hi);
        }
    }
#pragma unroll
    for (int c = 0; c < 8; ++c) {
        const int ct = ct0 + c;
        bf16x8 b[4];
#pragma unroll
        for (int kk = 0; kk < 4; ++kk)
            b[kk] = *(const bf16x8*)(Wpk + ((size_t)(ct * 4 + kk) * 64 + lane) * 8);
        f32x4 acc0 = {0.f, 0.f, 0.f, 0.f}, acc1 = {0.f, 0.f, 0.f, 0.f};
#pragma unroll
        for (int kk = 0; kk < 4; ++kk) {
            acc0 = __builtin_amdgcn_mfma_f32_16x16x32_bf16(a[0][kk], b[kk], acc0, 0, 0, 0);
            acc1 = __builtin_amdgcn_mfma_f32_16x16x32_bf16(a[1][kk], b[kk], acc1, 0, 0, 0);
        }
        const int col = ct * 16 + rlo;
#pragma unroll
        for (int r = 0; r < 4; ++r) {
            int row0 = rbase + (lane >> 4) * 4 + r;
            int row1 = row0 + 16;
            if (col < 256) {
                if (row0 < nrows) vp12[(size_t)row0 * 256 + col] = (ushort_t)f2bf(acc0[r]);
                if (row1 < nrows) vp12[(size_t)row1 * 256 + col] = (ushort_t)f2bf(acc1[r]);
            } else {
                if (row0 < nrows) v3p[(size_t)row0 * 128 + col - 256] = (ushort_t)f2bf(acc0[r]);
                if (row1 < nrows) v3p[(size_t)row1 * 128 + col - 256] = (ushort_t)f2bf(acc1[r]);
            }
        }
    }
}

// ---------------- kv stage 1: per-block partials, no atomics ----------------
__global__ __launch_bounds__(256) void kv_part(const float* __restrict__ h1,
        const float* __restrict__ pv, float* __restrict__ slab) {
    __shared__ float kf_s[8][DIM];
    __shared__ float v_s[8][DIM];
    const int tid = threadIdx.x;              // 256
    const int rpb = (NN + KVB - 1) / KVB;     // 59
    const int n0 = blockIdx.x * rpb;
    const int n1 = min(n0 + rpb, NN);
    const int base = tid * 8;
    const int hf = base >> 4;
    const int h = hf >> 4;
    const int d0 = base & 15;
    const int lr = tid >> 5;
    const int lg = tid & 31;
    const bool isK = lg < 16;
    const int le = (lg & 15) * 8;
    float acc[8];
#pragma unroll
    for (int i = 0; i < 8; ++i) acc[i] = 0.f;
    float zacc = 0.f;
    float4v p0 = {0,0,0,0}, p1 = {0,0,0,0};
    bool pvalid = false;
    {
        int n = n0 + lr;
        pvalid = n < n1;
        if (pvalid) {
            const float* src = isK ? (h1 + (size_t)n * 384 + 128 + le)
                                   : (pv + (size_t)n * 384 + le);
            p0 = *(const float4v*)src;
            p1 = *(const float4v*)(src + 4);
        }
    }
    for (int nt = n0; nt < n1; nt += 8) {
        __syncthreads();
        float4v c0 = p0, c1 = p1;
        if (!pvalid) { c0 = {0,0,0,0}; c1 = {0,0,0,0}; }
        else if (isK) {
#pragma unroll
            for (int i = 0; i < 4; ++i) {
                c0[i] = c0[i] > 0.f ? c0[i] + 1.f : expf(c0[i]);
                c1[i] = c1[i] > 0.f ? c1[i] + 1.f : expf(c1[i]);
            }
        }
        float* dst = (isK ? kf_s[lr] : v_s[lr]) + le;
        *(float4v*)dst = c0;
        *(float4v*)(dst + 4) = c1;
        __syncthreads();
        {
            int n = nt + 8 + lr;
            pvalid = n < n1;
            if (pvalid) {
                const float* src = isK ? (h1 + (size_t)n * 384 + 128 + le)
                                       : (pv + (size_t)n * 384 + le);
                p0 = *(const float4v*)src;
                p1 = *(const float4v*)(src + 4);
            }
        }
#pragma unroll
        for (int r = 0; r < 8; ++r) {
            float kfv = kf_s[r][hf];
#pragma unroll
            for (int i = 0; i < 8; ++i) acc[i] = fmaf(kfv, v_s[r][h * 16 + d0 + i], acc[i]);
            if (tid < 128) zacc += kf_s[r][tid];
        }
    }
    float* row = slab + (size_t)blockIdx.x * 2176;
#pragma unroll
    for (int i = 0; i < 8; ++i) row[base + i] = acc[i];
    if (tid < 128) row[2048 + tid] = zacc;
}

// ---------------- kv stage 2: kvz[i] = sum_b slab[b][i] ----------------
__global__ void kv_final(const float* __restrict__ slab, float* __restrict__ kvz) {
    int i = blockIdx.x * 256 + threadIdx.x;
    if (i >= 2176) return;
    float a[8];
#pragma unroll
    for (int j = 0; j < 8; ++j) a[j] = 0.f;
    for (int b = 0; b < KVB; b += 8) {
#pragma unroll
        for (int j = 0; j < 8; ++j) a[j] += slab[(size_t)(b + j) * 2176 + i];
    }
    kvz[i] = ((a[0] + a[1]) + (a[2] + a[3])) + ((a[4] + a[5]) + (a[6] + a[7]));
}

// ---------------- att(bf16)[n,h*16+d] = (qf . kv) / (qf . z + 1e-6) ----------------
__global__ void attn_apply(const float* __restrict__ h1, const float* __restrict__ kvz,
                           ushort_t* __restrict__ att) {
    __shared__ float kv_s[8 * 16 * 17];
    __shared__ float z_s[DIM];
    __shared__ float qf_s[8][DIM];
    const int tid = threadIdx.x;              // 128
    const int n0 = blockIdx.x * 8;
    for (int i = tid; i < 2048; i += 128) {
        int hf = i >> 4, d = i & 15;
        kv_s[hf * 17 + d] = kvz[i];
    }
    z_s[tid] = kvz[2048 + tid];
#pragma unroll
    for (int r = 0; r < 8; ++r) {
        float qv = h1[(size_t)(n0 + r) * 384 + tid];
        qf_s[r][tid] = qv > 0.f ? qv + 1.f : expf(qv);
    }
    __syncthreads();
    const int h = tid >> 4, d = tid & 15;
#pragma unroll
    for (int r = 0; r < 8; ++r) {
        float num = 0.f, den = 0.f;
#pragma unroll
        for (int f = 0; f < 16; ++f) {
            float q = qf_s[r][h * 16 + f];
            num = fmaf(q, kv_s[(h * 16 + f) * 17 + d], num);
            den = fmaf(q, z_s[h * 16 + f], den);
        }
        att[(size_t)(n0 + r) * DIM + tid] = (ushort_t)f2bf(num / (den + 1e-6f));
    }
}

// ---------------- vdot(bf16) + P-pack, col-pair vectorized ----------------
__global__ __launch_bounds__(256) void vecdot_reduce(const ushort_t* __restrict__ vp12,
        const float* __restrict__ vec, const float* __restrict__ pv,
        ushort_t* __restrict__ vdot, ushort_t* __restrict__ P) {
    const int tid = threadIdx.x;              // 256
    const int c2 = tid & 63;                  // cols {2c2, 2c2+1}
    const int sub = tid >> 6;                 // 0..3
    const int n0 = blockIdx.x * 8;
#pragma unroll
    for (int rr = 0; rr < 2; ++rr) {
        const int n = n0 + sub + rr * 4;
        float a0 = 0.f, a1 = 0.f;
#pragma unroll
        for (int c = 0; c < 3; ++c) {
            unsigned u1 = *(const unsigned*)(vp12 + (size_t)(3 * n + c) * 256 + 2 * c2);
            unsigned u2 = *(const unsigned*)(vp12 + (size_t)(3 * n + c) * 256 + 128 + 2 * c2);
            a0 = fmaf(bf2f((unsigned short)u1), bf2f((unsigned short)u2), a0);
            a1 = fmaf(bf2f((unsigned short)(u1 >> 16)), bf2f((unsigned short)(u2 >> 16)), a1);
        }
        *(unsigned*)(vdot + (size_t)n * 128 + 2 * c2) = pack2(a0, a1);
        float2 v1 = *(const float2*)(pv + (size_t)n * 384 + 128 + 2 * c2);
        float2 v2 = *(const float2*)(pv + (size_t)n * 384 + 256 + 2 * c2);
        s16x8 pk;
        pk[0] = f2bf(v2.x);
        pk[4] = f2bf(v2.y);
#pragma unroll
        for (int c = 0; c < 3; ++c) {
            float2 vc = *(const float2*)(vec + ((size_t)n * 3 + c) * 128 + 2 * c2);
            pk[1 + c] = f2bf(vc.x * v1.x);
            pk[5 + c] = f2bf(vc.y * v1.y);
        }
        *(s16x8*)(P + (size_t)n * 512 + (size_t)c2 * 8) = pk;
    }
}

// ---------------- edge CSR build ----------------
__global__ void hist_kernel(const int* __restrict__ eidx, int* __restrict__ cnt) {
    int e = blockIdx.x * 256 + threadIdx.x;
    if (e < EE) atomicAdd(&cnt[eidx[EE + e]], 1);
}

__global__ void scan_kernel(const int* __restrict__ cnt, int* __restrict__ off,
                            int* __restrict__ pos) {
    __shared__ int wsum[16];
    const int tid = threadIdx.x;              // 1024
    const int lane = tid & 63, wv = tid >> 6;
    const int PER = 30;
    const int base = tid * PER;
    int local[PER];
    int s = 0;
#pragma unroll
    for (int i = 0; i < PER; ++i) {
        int idx = base + i;
        int c = (idx < NN) ? cnt[idx] : 0;
        local[i] = s;
        s += c;
    }
    int incl = s;
#pragma unroll
    for (int d = 1; d < 64; d <<= 1) {
        int v = __shfl_up(incl, d, 64);
        if (lane >= d) incl += v;
    }
    if (lane == 63) wsum[wv] = incl;
    __syncthreads();
    if (wv == 0 && lane < 16) {
        int v = wsum[lane];
        int iv = v;
#pragma unroll
        for (int d = 1; d < 16; d <<= 1) {
            int u = __shfl_up(iv, d, 16);
            if (lane >= d) iv += u;
        }
        wsum[lane] = iv - v;
    }
    __syncthreads();
    const int carry = wsum[wv] + (incl - s);
#pragma unroll
    for (int i = 0; i < PER; ++i) {
        int idx = base + i;
        if (idx < NN) {
            int v = carry + local[i];
            off[idx] = v;
            pos[idx] = v;
        }
    }
    if (tid == 1023) off[NN] = wsum[15] + incl;
}

// scatter one 16B record per edge: {src, ev0, ev1, ev2}
__global__ void scatter_kernel(const int* __restrict__ eidx, const float* __restrict__ evec,
                               int* __restrict__ pos, int4* __restrict__ sorted4) {
    int e = blockIdx.x * 256 + threadIdx.x;
    if (e >= EE) return;
    int dst = eidx[EE + e];
    int src = eidx[e];
    float e0 = evec[(size_t)e * 3 + 0];
    float e1 = evec[(size_t)e * 3 + 1];
    float e2 = evec[(size_t)e * 3 + 2];
    int p = atomicAdd(&pos[dst], 1);
    sorted4[p] = make_int4(src, __float_as_int(e0), __float_as_int(e1), __float_as_int(e2));
}

// ---------------- segmented gather-reduce: grid (NN, 2), 4 groups x 64 lanes --------------
__global__ __launch_bounds__(256) void edge_agg_kernel(
        const int* __restrict__ off, const int4* __restrict__ sorted4,
        const ushort_t* __restrict__ P, ushort_t* __restrict__ agg) {
    __shared__ int srcs[128];
    __shared__ float evs[3][128];
    __shared__ float part[3][3][64];
    const int dst = blockIdx.x;
    const int tid = threadIdx.x;              // 256
    const int g = tid >> 6, l = tid & 63;
    const int o = blockIdx.y * 64 + l;
    const int j0 = off[dst], j1 = off[dst + 1];
    float a0 = 0.f, a1 = 0.f, a2 = 0.f;
    for (int jt = j0; jt < j1; jt += 128) {
        const int m = min(128, j1 - jt);
        if (tid < m) {
            int4 w = sorted4[jt + tid];
            srcs[tid] = w.x;
            evs[0][tid] = __int_as_float(w.y);
            evs[1][tid] = __int_as_float(w.z);
            evs[2][tid] = __int_as_float(w.w);
        }
        __syncthreads();
        int jj = g;
        for (; jj + 28 < m; jj += 32) {        // 8 edges per group-iteration
            s16x4 pk[8];
#pragma unroll
            for (int u = 0; u < 8; ++u)
                pk[u] = *(const s16x4*)(P + (size_t)srcs[jj + 4 * u] * 512 + o * 4);
#pragma unroll
            for (int u = 0; u < 8; ++u) {
                int e = jj + 4 * u;
                float v2 = bf2f((unsigned short)pk[u][0]);
                a0 += fmaf(evs[0][e], v2, bf2f((unsigned short)pk[u][1]));
                a1 += fmaf(evs[1][e], v2, bf2f((unsigned short)pk[u][2]));
                a2 += fmaf(evs[2][e], v2, bf2f((unsigned short)pk[u][3]));
            }
        }
        for (; jj < m; jj += 4) {
            s16x4 pk = *(const s16x4*)(P + (size_t)srcs[jj] * 512 + o * 4);
            float v2 = bf2f((unsigned short)pk[0]);
            a0 += fmaf(evs[0][jj], v2, bf2f((unsigned short)pk[1]));
            a1 += fmaf(evs[1][jj], v2, bf2f((unsigned short)pk[2]));
            a2 += fmaf(evs[2][jj], v2, bf2f((unsigned short)pk[3]));
        }
        __syncthreads();
    }
    if (g) { part[g - 1][0][l] = a0; part[g - 1][1][l] = a1; part[g - 1][2][l] = a2; }
    __syncthreads();
    if (g == 0) {
        a0 += part[0][0][l] + part[1][0][l] + part[2][0][l];
        a1 += part[0][1][l] + part[1][1][l] + part[2][1][l];
        a2 += part[0][2][l] + part[1][2][l] + part[2][2][l];
        agg[((size_t)dst * 3 + 0) * DIM + o] = (ushort_t)f2bf(a0);
        agg[((size_t)dst * 3 + 1) * DIM + o] = (ushort_t)f2bf(a1);
        agg[((size_t)dst * 3 + 2) * DIM + o] = (ushort_t)f2bf(a2);
    }
}

// ---------------- out_x = non_att + ((att + vdot*o2 + o3) @ W_fco + b_fco)*ew (MFMA) ------
__global__ __launch_bounds__(256) void outx_mfma(const ushort_t* __restrict__ att,
        const ushort_t* __restrict__ vdot, const ushort_t* __restrict__ o,
        const short* __restrict__ Wpk, const float* __restrict__ bfco,
        const float* __restrict__ h1, const float* __restrict__ ew,
        float* __restrict__ outx) {
    const int lane = threadIdx.x & 63;
    const int wid = threadIdx.x >> 6;
    const int rbase = blockIdx.x * 128 + wid * 32;
    if (rbase >= NN) return;
    const int ct0 = blockIdx.y * 4;
    const int rlo = lane & 15, khi = (lane >> 4) * 8;
    bf16x8 a[2][4];
#pragma unroll
    for (int t = 0; t < 2; ++t) {
        int row = min(rbase + t * 16 + rlo, NN - 1);
        const ushort_t* pa = att + (size_t)row * 128 + khi;
        const ushort_t* pd = vdot + (size_t)row * 128 + khi;
        const ushort_t* po = o + (size_t)row * 384 + khi;
#pragma unroll
        for (int kk = 0; kk < 4; ++kk) {
            int kb = kk * 32;
            float4v al, ah, dl, dh, o2l, o2h, o3l, o3h;
            bf8_to_f(*(const bf16x8*)(pa + kb), al, ah);
            bf8_to_f(*(const bf16x8*)(pd + kb), dl, dh);
            bf8_to_f(*(const bf16x8*)(po + 128 + kb), o2l, o2h);
            bf8_to_f(*(const bf16x8*)(po + 256 + kb), o3l, o3h);
            a[t][kk] = cvt8(al + dl * o2l + o3l, ah + dh * o2h + o3h);
        }
    }
    float ewv[2][4];
#pragma unroll
    for (int t = 0; t < 2; ++t)
#pragma unroll
        for (int r = 0; r < 4; ++r)
            ewv[t][r] = ew[min(rbase + t * 16 + (lane >> 4) * 4 + r, NN - 1)];
#pragma unroll
    for (int c = 0; c < 4; ++c) {
        const int ct = ct0 + c;
        bf16x8 b[4];
#pragma unroll
        for (int kk = 0; kk < 4; ++kk)
            b[kk] = *(const bf16x8*)(Wpk + ((size_t)(ct * 4 + kk) * 64 + lane) * 8);
        f32x4 acc0 = {0.f, 0.f, 0.f, 0.f}, acc1 = {0.f, 0.f, 0.f, 0.f};
#pragma unroll
        for (int kk = 0; kk < 4; ++kk) {
            acc0 = __builtin_amdgcn_mfma_f32_16x16x32_bf16(a[0][kk], b[kk], acc0, 0, 0, 0);
            acc1 = __builtin_amdgcn_mfma_f32_16x16x32_bf16(a[1][kk], b[kk], acc1, 0, 0, 0);
        }
        const int col = ct * 16 + rlo;
        const float bv = bfco[col];
#pragma unroll
        for (int r = 0; r < 4; ++r) {
            int row0 = rbase + (lane >> 4) * 4 + r;
            if (row0 < NN)
                outx[(size_t)row0 * 128 + col] =
                    h1[(size_t)row0 * 384 + 256 + col] + (acc0[r] + bv) * ewv[0][r];
            int row1 = row0 + 16;
            if (row1 < NN)
                outx[(size_t)row1 * 128 + col] =
                    h1[(size_t)row1 * 384 + 256 + col] + (acc1[r] + bv) * ewv[1][r];
        }
    }
}

// ---------------- LN: dvn(bf16) = LN(v3p*o1 + agg) ; one row per wave -----------------
__global__ __launch_bounds__(256) void outvec_ln(const ushort_t* __restrict__ v3p,
        const ushort_t* __restrict__ o, const ushort_t* __restrict__ agg,
        const float* __restrict__ ln_scale, const float* __restrict__ ln_bias,
        ushort_t* __restrict__ dvn) {
    const int tid = threadIdx.x;              // 256 = 4 rows x 64 lanes
    const int c2 = tid & 63;
    const int row = blockIdx.x * 4 + (tid >> 6);
    const int n = row / 3;
    unsigned uv3 = *(const unsigned*)(v3p + (size_t)row * 128 + 2 * c2);
    unsigned uo1 = *(const unsigned*)(o + (size_t)n * 384 + 2 * c2);
    unsigned uag = *(const unsigned*)(agg + (size_t)row * 128 + 2 * c2);
    float dv0 = fmaf(bf2f((unsigned short)uv3), bf2f((unsigned short)uo1),
                     bf2f((unsigned short)uag));
    float dv1 = fmaf(bf2f((unsigned short)(uv3 >> 16)), bf2f((unsigned short)(uo1 >> 16)),
                     bf2f((unsigned short)(uag >> 16)));
    float s = dv0 + dv1;
    float s2 = fmaf(dv0, dv0, dv1 * dv1);
#pragma unroll
    for (int d = 1; d < 64; d <<= 1) {
        s += __shfl_xor(s, d, 64);
        s2 += __shfl_xor(s2, d, 64);
    }
    float mu = s * (1.f / 128.f);
    float rstd = rsqrtf(s2 * (1.f / 128.f) - mu * mu + 1e-5f);
    float r0 = fmaf((dv0 - mu) * rstd, ln_scale[2 * c2], ln_bias[2 * c2]);
    float r1 = fmaf((dv1 - mu) * rstd, ln_scale[2 * c2 + 1], ln_bias[2 * c2 + 1]);
    *(unsigned*)(dvn + (size_t)row * 128 + 2 * c2) = pack2(r0, r1);
}

extern "C" void kernel_launch(void* const* d_in, const int* in_sizes, int n_in,
                              void* d_out, int out_size, void* d_ws, size_t ws_size,
                              hipStream_t stream) {
    const float* x          = (const float*)d_in[0];
    const float* vec        = (const float*)d_in[1];
    const float* edge_vec   = (const float*)d_in[2];
    const float* edge_weight= (const float*)d_in[3];
    const float* W_fc1      = (const float*)d_in[4];
    const float* W_fcv      = (const float*)d_in[5];
    const float* b_fcv      = (const float*)d_in[6];
    const float* W_fco      = (const float*)d_in[7];
    const float* b_fco      = (const float*)d_in[8];
    const float* W_out      = (const float*)d_in[9];
    const float* W_vecproj  = (const float*)d_in[10];
    const float* W_equiv    = (const float*)d_in[11];
    const float* ln_scale   = (const float*)d_in[12];
    const float* ln_bias    = (const float*)d_in[13];
    const int*   edge_index = (const int*)d_in[14];

    float* out_x   = (float*)d_out;
    float* out_vec = out_x + (size_t)NN * DIM;
    ushort_t* Pb = (ushort_t*)d_out;           // N x 512 bf16, alias (dead before out writes)

    float* ws   = (float*)d_ws;
    float* h1   = ws;                                   // N*384 f32
    float* pv   = h1 + 11520000;                        // N*384 f32
    ushort_t* att_b  = (ushort_t*)(pv + 11520000);      // N*128 bf16   (1.92M f)
    ushort_t* vdot_b = att_b + 3840000;                 // N*128 bf16   (1.92M f)
    ushort_t* o_b    = vdot_b + 3840000;                // N*384 bf16   (5.76M f)
    ushort_t* agg_b  = o_b + 11520000;                  // 3N*128 bf16  (5.76M f)
    ushort_t* v3p_b  = agg_b + 11520000;                // 3N*128 bf16  (5.76M f)
    float* kvz  = (float*)(v3p_b + 11520000);           // 2176 f32
    // aliases (stream-ordered dead ranges):
    ushort_t* vp12_b = o_b;                             // 3N*256 bf16 spans o_b..agg_b
    float* slab = (float*)o_b;                          // KVB*2176 f32, dead before vp_gemm
    ushort_t* dvn_b = (ushort_t*)pv;                    // 3N*128 bf16, pv dead by then
    int* cnt    = (int*)(kvz + 2176);                   // N
    int* off    = cnt + NN;                             // N+1
    int* pos    = off + NN + 1;                         // N
    size_t soff = ((size_t)(pos + NN - (int*)ws) + 3) & ~(size_t)3;    // 16B align
    int4* sorted4 = (int4*)((int*)ws + soff);           // E * 16B
    short* Wpk  = (short*)((int*)ws + soff + (size_t)4 * EE);          // 448 frags
    short* pk_fc1  = Wpk;
    short* pk_fcv  = Wpk + 96 * 512;
    short* pk_wout = Wpk + 192 * 512;
    short* pk_vp   = Wpk + 288 * 512;          // unified 384-col vecproj (96 frags)
    short* pk_fco  = Wpk + 384 * 512;
    short* pk_weq  = Wpk + 416 * 512;

    hipMemsetAsync(cnt, 0, NN * sizeof(int), stream);

    pack_all<<<112, 256, 0, stream>>>(W_fc1, W_fcv, W_out, W_vecproj, W_fco, W_equiv, Wpk);

    // CSR build (depends only on edge_index / edge_vec)
    hist_kernel<<<(EE + 255) / 256, 256, 0, stream>>>(edge_index, cnt);
    scan_kernel<<<1, 1024, 0, stream>>>(cnt, off, pos);
    scatter_kernel<<<(EE + 255) / 256, 256, 0, stream>>>(edge_index, edge_vec, pos, sorted4);

    const int gN = (NN + 127) / 128;           // 235
    const int g3N = (3 * NN + 127) / 128;      // 704
    mfma_gemm<384, 8, false, float, float><<<dim3(gN, 3), 256, 0, stream>>>(x, pk_fc1, nullptr, h1, NN);
    mfma_gemm<384, 8, true, float, float><<<dim3(gN, 3), 256, 0, stream>>>(x, pk_fcv, b_fcv, pv, NN);
    kv_part<<<KVB, 256, 0, stream>>>(h1, pv, slab);
    kv_final<<<9, 256, 0, stream>>>(slab, kvz);
    attn_apply<<<NN / 8, 128, 0, stream>>>(h1, kvz, att_b);
    vp_gemm<<<dim3(g3N, 3), 256, 0, stream>>>(vec, pk_vp, vp12_b, v3p_b, 3 * NN);
    vecdot_reduce<<<NN / 8, 256, 0, stream>>>(vp12_b, vec, pv, vdot_b, Pb);
    mfma_gemm<384, 8, false, ushort_t, ushort_t><<<dim3(gN, 3), 256, 0, stream>>>(att_b, pk_wout, nullptr, o_b, NN);
    edge_agg_kernel<<<dim3(NN, 2), 256, 0, stream>>>(off, sorted4, Pb, agg_b);
    outx_mfma<<<dim3(gN, 2), 256, 0, stream>>>(att_b, vdot_b, o_b, pk_fco, b_fco, h1, edge_weight, out_x);
    outvec_ln<<<(3 * NN) / 4, 256, 0, stream>>>(v3p_b, o_b, agg_b, ln_scale, ln_bias, dvn_b);
    mfma_gemm<128, 4, false, ushort_t, float><<<dim3(g3N, 2), 256, 0, stream>>>(dvn_b, pk_weq, nullptr, out_vec, 3 * NN);
}

// Round 10
// 446.437 us; speedup vs baseline: 1.0500x; 1.0500x over previous
//
#include <hip/hip_runtime.h>
#include <math.h>

#define NN 30000
#define EE 480000
#define DIM 128
#define KVB 512   // kv_part blocks

typedef __attribute__((ext_vector_type(8))) short bf16x8;
typedef __attribute__((ext_vector_type(8))) short s16x8;
typedef __attribute__((ext_vector_type(4))) short s16x4;
typedef __attribute__((ext_vector_type(4))) float f32x4;
typedef __attribute__((ext_vector_type(4))) float float4v;
typedef unsigned short ushort_t;

__device__ inline short f2bf(float f) {      // RNE f32 -> bf16
    union { float f; unsigned u; } v; v.f = f;
    unsigned u = v.u;
    u += 0x7fffu + ((u >> 16) & 1u);
    return (short)(u >> 16);
}
__device__ inline float bf2f(unsigned short u) {
    union { unsigned u; float f; } v; v.u = ((unsigned)u) << 16; return v.f;
}
__device__ inline unsigned pack2(float a, float b) {
    return (unsigned)(ushort_t)f2bf(a) | ((unsigned)(ushort_t)f2bf(b) << 16);
}

__device__ inline bf16x8 cvt8(float4v lo, float4v hi) {
    bf16x8 r;
    r[0] = f2bf(lo[0]); r[1] = f2bf(lo[1]); r[2] = f2bf(lo[2]); r[3] = f2bf(lo[3]);
    r[4] = f2bf(hi[0]); r[5] = f2bf(hi[1]); r[6] = f2bf(hi[2]); r[7] = f2bf(hi[3]);
    return r;
}
__device__ inline void bf8_to_f(bf16x8 v, float4v& lo, float4v& hi) {
#pragma unroll
    for (int i = 0; i < 4; ++i) {
        lo[i] = bf2f((unsigned short)v[i]);
        hi[i] = bf2f((unsigned short)v[4 + i]);
    }
}

// ---------------- weight pre-pack (fragment-major bf16) ----------------
__global__ void pack_all(const float* __restrict__ fc1, const float* __restrict__ fcv,
                         const float* __restrict__ wout, const float* __restrict__ wvp,
                         const float* __restrict__ fco, const float* __restrict__ weq,
                         short* __restrict__ Wpk) {
    int fid = blockIdx.x * 4 + (threadIdx.x >> 6);
    int lane = threadIdx.x & 63;
    const float* src; int Nsrc, c0, f;
    if (fid < 96)       { src = fc1;  Nsrc = 384; c0 = 0;   f = fid; }
    else if (fid < 192) { src = fcv;  Nsrc = 384; c0 = 0;   f = fid - 96; }
    else if (fid < 288) { src = wout; Nsrc = 384; c0 = 0;   f = fid - 192; }
    else if (fid < 352) { src = wvp;  Nsrc = 384; c0 = 0;   f = fid - 288; }
    else if (fid < 384) { src = wvp;  Nsrc = 384; c0 = 256; f = fid - 352; }
    else if (fid < 416) { src = fco;  Nsrc = 128; c0 = 0;   f = fid - 384; }
    else                { src = weq;  Nsrc = 128; c0 = 0;   f = fid - 416; }
    int ct = f >> 2, kk = f & 3;
    int k0 = kk * 32 + (lane >> 4) * 8;
    int col = c0 + ct * 16 + (lane & 15);
    bf16x8 v;
#pragma unroll
    for (int i = 0; i < 8; ++i) v[i] = f2bf(src[(size_t)(k0 + i) * Nsrc + col]);
    *(bf16x8*)(Wpk + ((size_t)fid * 64 + lane) * 8) = v;
}

// ---------------- generic MFMA GEMM with col-tile blocking (blockIdx.y) -------------------
template<int COLS, int CT_PER, bool BIAS, typename InT, typename OutT>
__global__ __launch_bounds__(256) void mfma_gemm(const InT* __restrict__ in,
        const short* __restrict__ Wpk, const float* __restrict__ bias,
        OutT* __restrict__ out, int nrows) {
    const int lane = threadIdx.x & 63;
    const int wid = threadIdx.x >> 6;
    const int rbase = blockIdx.x * 128 + wid * 32;
    if (rbase >= nrows) return;
    const int ct0 = blockIdx.y * CT_PER;
    const int rlo = lane & 15, khi = (lane >> 4) * 8;
    bf16x8 a[2][4];
#pragma unroll
    for (int t = 0; t < 2; ++t) {
        int row = min(rbase + t * 16 + rlo, nrows - 1);
        const InT* rp = in + (size_t)row * 128 + khi;
#pragma unroll
        for (int kk = 0; kk < 4; ++kk) {
            if constexpr (sizeof(InT) == 4) {
                float4v lo = *(const float4v*)(rp + kk * 32);
                float4v hi = *(const float4v*)(rp + kk * 32 + 4);
                a[t][kk] = cvt8(lo, hi);
            } else {
                a[t][kk] = *(const bf16x8*)(rp + kk * 32);
            }
        }
    }
#pragma unroll
    for (int c = 0; c < CT_PER; ++c) {
        const int ct = ct0 + c;
        bf16x8 b[4];
#pragma unroll
        for (int kk = 0; kk < 4; ++kk)
            b[kk] = *(const bf16x8*)(Wpk + ((size_t)(ct * 4 + kk) * 64 + lane) * 8);
        f32x4 acc0 = {0.f, 0.f, 0.f, 0.f}, acc1 = {0.f, 0.f, 0.f, 0.f};
#pragma unroll
        for (int kk = 0; kk < 4; ++kk) {
            acc0 = __builtin_amdgcn_mfma_f32_16x16x32_bf16(a[0][kk], b[kk], acc0, 0, 0, 0);
            acc1 = __builtin_amdgcn_mfma_f32_16x16x32_bf16(a[1][kk], b[kk], acc1, 0, 0, 0);
        }
        const int col = ct * 16 + rlo;
        const float bv = BIAS ? bias[col] : 0.f;
#pragma unroll
        for (int r = 0; r < 4; ++r) {
            int row0 = rbase + (lane >> 4) * 4 + r;
            int row1 = row0 + 16;
            if constexpr (sizeof(OutT) == 4) {
                if (row0 < nrows) out[(size_t)row0 * COLS + col] = acc0[r] + bv;
                if (row1 < nrows) out[(size_t)row1 * COLS + col] = acc1[r] + bv;
            } else {
                if (row0 < nrows) out[(size_t)row0 * COLS + col] = (OutT)f2bf(acc0[r] + bv);
                if (row1 < nrows) out[(size_t)row1 * COLS + col] = (OutT)f2bf(acc1[r] + bv);
            }
        }
    }
}

// ---------------- vecproj GEMM (384 cols): cols<256 -> vp12 bf16, cols>=256 -> v3p bf16 ---
__global__ __launch_bounds__(256) void vp_gemm(const float* __restrict__ in,
        const short* __restrict__ Wpk, ushort_t* __restrict__ vp12,
        ushort_t* __restrict__ v3p, int nrows) {
    const int lane = threadIdx.x & 63;
    const int wid = threadIdx.x >> 6;
    const int rbase = blockIdx.x * 128 + wid * 32;
    if (rbase >= nrows) return;
    const int ct0 = blockIdx.y * 8;
    const int rlo = lane & 15, khi = (lane >> 4) * 8;
    bf16x8 a[2][4];
#pragma unroll
    for (int t = 0; t < 2; ++t) {
        int row = min(rbase + t * 16 + rlo, nrows - 1);
        const float* rp = in + (size_t)row * 128 + khi;
#pragma unroll
        for (int kk = 0; kk < 4; ++kk) {
            float4v lo = *(const float4v*)(rp + kk * 32);
            float4v hi = *(const float4v*)(rp + kk * 32 + 4);
            a[t][kk] = cvt8(lo, hi);
        }
    }
#pragma unroll
    for (int c = 0; c < 8; ++c) {
        const int ct = ct0 + c;
        bf16x8 b[4];
#pragma unroll
        for (int kk = 0; kk < 4; ++kk)
            b[kk] = *(const bf16x8*)(Wpk + ((size_t)(ct * 4 + kk) * 64 + lane) * 8);
        f32x4 acc0 = {0.f, 0.f, 0.f, 0.f}, acc1 = {0.f, 0.f, 0.f, 0.f};
#pragma unroll
        for (int kk = 0; kk < 4; ++kk) {
            acc0 = __builtin_amdgcn_mfma_f32_16x16x32_bf16(a[0][kk], b[kk], acc0, 0, 0, 0);
            acc1 = __builtin_amdgcn_mfma_f32_16x16x32_bf16(a[1][kk], b[kk], acc1, 0, 0, 0);
        }
        const int col = ct * 16 + rlo;
#pragma unroll
        for (int r = 0; r < 4; ++r) {
            int row0 = rbase + (lane >> 4) * 4 + r;
            int row1 = row0 + 16;
            if (col < 256) {
                if (row0 < nrows) vp12[(size_t)row0 * 256 + col] = (ushort_t)f2bf(acc0[r]);
                if (row1 < nrows) vp12[(size_t)row1 * 256 + col] = (ushort_t)f2bf(acc1[r]);
            } else {
                if (row0 < nrows) v3p[(size_t)row0 * 128 + col - 256] = (ushort_t)f2bf(acc0[r]);
                if (row1 < nrows) v3p[(size_t)row1 * 128 + col - 256] = (ushort_t)f2bf(acc1[r]);
            }
        }
    }
}

// ---------------- kv stage 1: per-block partials, no atomics ----------------
__global__ __launch_bounds__(256) void kv_part(const float* __restrict__ h1,
        const float* __restrict__ pv, float* __restrict__ slab) {
    __shared__ float kf_s[8][DIM];
    __shared__ float v_s[8][DIM];
    const int tid = threadIdx.x;              // 256
    const int rpb = (NN + KVB - 1) / KVB;     // 59
    const int n0 = blockIdx.x * rpb;
    const int n1 = min(n0 + rpb, NN);
    const int base = tid * 8;
    const int hf = base >> 4;
    const int h = hf >> 4;
    const int d0 = base & 15;
    const int lr = tid >> 5;
    const int lg = tid & 31;
    const bool isK = lg < 16;
    const int le = (lg & 15) * 8;
    float acc[8];
#pragma unroll
    for (int i = 0; i < 8; ++i) acc[i] = 0.f;
    float zacc = 0.f;
    float4v p0 = {0,0,0,0}, p1 = {0,0,0,0};
    bool pvalid = false;
    {
        int n = n0 + lr;
        pvalid = n < n1;
        if (pvalid) {
            const float* src = isK ? (h1 + (size_t)n * 384 + 128 + le)
                                   : (pv + (size_t)n * 384 + le);
            p0 = *(const float4v*)src;
            p1 = *(const float4v*)(src + 4);
        }
    }
    for (int nt = n0; nt < n1; nt += 8) {
        __syncthreads();
        float4v c0 = p0, c1 = p1;
        if (!pvalid) { c0 = {0,0,0,0}; c1 = {0,0,0,0}; }
        else if (isK) {
#pragma unroll
            for (int i = 0; i < 4; ++i) {
                c0[i] = c0[i] > 0.f ? c0[i] + 1.f : expf(c0[i]);
                c1[i] = c1[i] > 0.f ? c1[i] + 1.f : expf(c1[i]);
            }
        }
        float* dst = (isK ? kf_s[lr] : v_s[lr]) + le;
        *(float4v*)dst = c0;
        *(float4v*)(dst + 4) = c1;
        __syncthreads();
        {
            int n = nt + 8 + lr;
            pvalid = n < n1;
            if (pvalid) {
                const float* src = isK ? (h1 + (size_t)n * 384 + 128 + le)
                                       : (pv + (size_t)n * 384 + le);
                p0 = *(const float4v*)src;
                p1 = *(const float4v*)(src + 4);
            }
        }
#pragma unroll
        for (int r = 0; r < 8; ++r) {
            float kfv = kf_s[r][hf];
#pragma unroll
            for (int i = 0; i < 8; ++i) acc[i] = fmaf(kfv, v_s[r][h * 16 + d0 + i], acc[i]);
            if (tid < 128) zacc += kf_s[r][tid];
        }
    }
    float* row = slab + (size_t)blockIdx.x * 2176;
#pragma unroll
    for (int i = 0; i < 8; ++i) row[base + i] = acc[i];
    if (tid < 128) row[2048 + tid] = zacc;
}

// ---------------- kv stage 2: kvz[i] = sum_b slab[b][i] ----------------
__global__ void kv_final(const float* __restrict__ slab, float* __restrict__ kvz) {
    int i = blockIdx.x * 256 + threadIdx.x;
    if (i >= 2176) return;
    float a[8];
#pragma unroll
    for (int j = 0; j < 8; ++j) a[j] = 0.f;
    for (int b = 0; b < KVB; b += 8) {
#pragma unroll
        for (int j = 0; j < 8; ++j) a[j] += slab[(size_t)(b + j) * 2176 + i];
    }
    kvz[i] = ((a[0] + a[1]) + (a[2] + a[3])) + ((a[4] + a[5]) + (a[6] + a[7]));
}

// ---------------- att(bf16)[n,h*16+d] = (qf . kv) / (qf . z + 1e-6) ----------------
__global__ void attn_apply(const float* __restrict__ h1, const float* __restrict__ kvz,
                           ushort_t* __restrict__ att) {
    __shared__ float kv_s[8 * 16 * 17];
    __shared__ float z_s[DIM];
    __shared__ float qf_s[8][DIM];
    const int tid = threadIdx.x;              // 128
    const int n0 = blockIdx.x * 8;
    for (int i = tid; i < 2048; i += 128) {
        int hf = i >> 4, d = i & 15;
        kv_s[hf * 17 + d] = kvz[i];
    }
    z_s[tid] = kvz[2048 + tid];
#pragma unroll
    for (int r = 0; r < 8; ++r) {
        float qv = h1[(size_t)(n0 + r) * 384 + tid];
        qf_s[r][tid] = qv > 0.f ? qv + 1.f : expf(qv);
    }
    __syncthreads();
    const int h = tid >> 4, d = tid & 15;
#pragma unroll
    for (int r = 0; r < 8; ++r) {
        float num = 0.f, den = 0.f;
#pragma unroll
        for (int f = 0; f < 16; ++f) {
            float q = qf_s[r][h * 16 + f];
            num = fmaf(q, kv_s[(h * 16 + f) * 17 + d], num);
            den = fmaf(q, z_s[h * 16 + f], den);
        }
        att[(size_t)(n0 + r) * DIM + tid] = (ushort_t)f2bf(num / (den + 1e-6f));
    }
}

// ---------------- vdot(bf16) + P-pack, col-pair vectorized ----------------
__global__ __launch_bounds__(256) void vecdot_reduce(const ushort_t* __restrict__ vp12,
        const float* __restrict__ vec, const float* __restrict__ pv,
        ushort_t* __restrict__ vdot, ushort_t* __restrict__ P) {
    const int tid = threadIdx.x;              // 256
    const int c2 = tid & 63;                  // cols {2c2, 2c2+1}
    const int sub = tid >> 6;                 // 0..3
    const int n0 = blockIdx.x * 8;
#pragma unroll
    for (int rr = 0; rr < 2; ++rr) {
        const int n = n0 + sub + rr * 4;
        float a0 = 0.f, a1 = 0.f;
#pragma unroll
        for (int c = 0; c < 3; ++c) {
            unsigned u1 = *(const unsigned*)(vp12 + (size_t)(3 * n + c) * 256 + 2 * c2);
            unsigned u2 = *(const unsigned*)(vp12 + (size_t)(3 * n + c) * 256 + 128 + 2 * c2);
            a0 = fmaf(bf2f((unsigned short)u1), bf2f((unsigned short)u2), a0);
            a1 = fmaf(bf2f((unsigned short)(u1 >> 16)), bf2f((unsigned short)(u2 >> 16)), a1);
        }
        *(unsigned*)(vdot + (size_t)n * 128 + 2 * c2) = pack2(a0, a1);
        float2 v1 = *(const float2*)(pv + (size_t)n * 384 + 128 + 2 * c2);
        float2 v2 = *(const float2*)(pv + (size_t)n * 384 + 256 + 2 * c2);
        s16x8 pk;
        pk[0] = f2bf(v2.x);
        pk[4] = f2bf(v2.y);
#pragma unroll
        for (int c = 0; c < 3; ++c) {
            float2 vc = *(const float2*)(vec + ((size_t)n * 3 + c) * 128 + 2 * c2);
            pk[1 + c] = f2bf(vc.x * v1.x);
            pk[5 + c] = f2bf(vc.y * v1.y);
        }
        *(s16x8*)(P + (size_t)n * 512 + (size_t)c2 * 8) = pk;
    }
}

// ---------------- edge CSR build ----------------
__global__ void hist_kernel(const int* __restrict__ eidx, int* __restrict__ cnt) {
    int e = blockIdx.x * 256 + threadIdx.x;
    if (e < EE) atomicAdd(&cnt[eidx[EE + e]], 1);
}

__global__ void scan_kernel(const int* __restrict__ cnt, int* __restrict__ off,
                            int* __restrict__ pos) {
    __shared__ int wsum[16];
    const int tid = threadIdx.x;              // 1024
    const int lane = tid & 63, wv = tid >> 6;
    const int PER = 30;
    const int base = tid * PER;
    int local[PER];
    int s = 0;
#pragma unroll
    for (int i = 0; i < PER; ++i) {
        int idx = base + i;
        int c = (idx < NN) ? cnt[idx] : 0;
        local[i] = s;
        s += c;
    }
    int incl = s;
#pragma unroll
    for (int d = 1; d < 64; d <<= 1) {
        int v = __shfl_up(incl, d, 64);
        if (lane >= d) incl += v;
    }
    if (lane == 63) wsum[wv] = incl;
    __syncthreads();
    if (wv == 0 && lane < 16) {
        int v = wsum[lane];
        int iv = v;
#pragma unroll
        for (int d = 1; d < 16; d <<= 1) {
            int u = __shfl_up(iv, d, 16);
            if (lane >= d) iv += u;
        }
        wsum[lane] = iv - v;
    }
    __syncthreads();
    const int carry = wsum[wv] + (incl - s);
#pragma unroll
    for (int i = 0; i < PER; ++i) {
        int idx = base + i;
        if (idx < NN) {
            int v = carry + local[i];
            off[idx] = v;
            pos[idx] = v;
        }
    }
    if (tid == 1023) off[NN] = wsum[15] + incl;
}

// scatter one 16B record per edge: {src, ev0, ev1, ev2}
__global__ void scatter_kernel(const int* __restrict__ eidx, const float* __restrict__ evec,
                               int* __restrict__ pos, int4* __restrict__ sorted4) {
    int e = blockIdx.x * 256 + threadIdx.x;
    if (e >= EE) return;
    int dst = eidx[EE + e];
    int src = eidx[e];
    float e0 = evec[(size_t)e * 3 + 0];
    float e1 = evec[(size_t)e * 3 + 1];
    float e2 = evec[(size_t)e * 3 + 2];
    int p = atomicAdd(&pos[dst], 1);
    sorted4[p] = make_int4(src, __float_as_int(e0), __float_as_int(e1), __float_as_int(e2));
}

// ---------------- segmented gather-reduce: one block (2 groups x 128 lanes) per dst -------
// round-8 proven structure; 8-deep batched loads; bf16 agg output.
__global__ __launch_bounds__(256) void edge_agg_kernel(
        const int* __restrict__ off, const int4* __restrict__ sorted4,
        const ushort_t* __restrict__ P, ushort_t* __restrict__ agg) {
    __shared__ int srcs[128];
    __shared__ float evs[3][128];
    __shared__ float part[3][128];
    const int dst = blockIdx.x;
    const int tid = threadIdx.x;              // 256
    const int g = tid >> 7, o = tid & 127;
    const int j0 = off[dst], j1 = off[dst + 1];
    float a0 = 0.f, a1 = 0.f, a2 = 0.f;
    for (int jt = j0; jt < j1; jt += 128) {
        const int m = min(128, j1 - jt);
        if (tid < m) {
            int4 w = sorted4[jt + tid];
            srcs[tid] = w.x;
            evs[0][tid] = __int_as_float(w.y);
            evs[1][tid] = __int_as_float(w.z);
            evs[2][tid] = __int_as_float(w.w);
        }
        __syncthreads();
        int jj = g;
        for (; jj + 14 < m; jj += 16) {        // 8 edges per group-iteration
            s16x4 pk[8];
#pragma unroll
            for (int u = 0; u < 8; ++u)
                pk[u] = *(const s16x4*)(P + (size_t)srcs[jj + 2 * u] * 512 + o * 4);
#pragma unroll
            for (int u = 0; u < 8; ++u) {
                int e = jj + 2 * u;
                float v2 = bf2f((unsigned short)pk[u][0]);
                a0 += fmaf(evs[0][e], v2, bf2f((unsigned short)pk[u][1]));
                a1 += fmaf(evs[1][e], v2, bf2f((unsigned short)pk[u][2]));
                a2 += fmaf(evs[2][e], v2, bf2f((unsigned short)pk[u][3]));
            }
        }
        for (; jj < m; jj += 2) {
            s16x4 pk = *(const s16x4*)(P + (size_t)srcs[jj] * 512 + o * 4);
            float v2 = bf2f((unsigned short)pk[0]);
            a0 += fmaf(evs[0][jj], v2, bf2f((unsigned short)pk[1]));
            a1 += fmaf(evs[1][jj], v2, bf2f((unsigned short)pk[2]));
            a2 += fmaf(evs[2][jj], v2, bf2f((unsigned short)pk[3]));
        }
        __syncthreads();
    }
    if (g == 1) { part[0][o] = a0; part[1][o] = a1; part[2][o] = a2; }
    __syncthreads();
    if (g == 0) {
        a0 += part[0][o]; a1 += part[1][o]; a2 += part[2][o];
        agg[((size_t)dst * 3 + 0) * DIM + o] = (ushort_t)f2bf(a0);
        agg[((size_t)dst * 3 + 1) * DIM + o] = (ushort_t)f2bf(a1);
        agg[((size_t)dst * 3 + 2) * DIM + o] = (ushort_t)f2bf(a2);
    }
}

// ---------------- out_x = non_att + ((att + vdot*o2 + o3) @ W_fco + b_fco)*ew (MFMA) ------
__global__ __launch_bounds__(256) void outx_mfma(const ushort_t* __restrict__ att,
        const ushort_t* __restrict__ vdot, const ushort_t* __restrict__ o,
        const short* __restrict__ Wpk, const float* __restrict__ bfco,
        const float* __restrict__ h1, const float* __restrict__ ew,
        float* __restrict__ outx) {
    const int lane = threadIdx.x & 63;
    const int wid = threadIdx.x >> 6;
    const int rbase = blockIdx.x * 128 + wid * 32;
    if (rbase >= NN) return;
    const int ct0 = blockIdx.y * 4;
    const int rlo = lane & 15, khi = (lane >> 4) * 8;
    bf16x8 a[2][4];
#pragma unroll
    for (int t = 0; t < 2; ++t) {
        int row = min(rbase + t * 16 + rlo, NN - 1);
        const ushort_t* pa = att + (size_t)row * 128 + khi;
        const ushort_t* pd = vdot + (size_t)row * 128 + khi;
        const ushort_t* po = o + (size_t)row * 384 + khi;
#pragma unroll
        for (int kk = 0; kk < 4; ++kk) {
            int kb = kk * 32;
            float4v al, ah, dl, dh, o2l, o2h, o3l, o3h;
            bf8_to_f(*(const bf16x8*)(pa + kb), al, ah);
            bf8_to_f(*(const bf16x8*)(pd + kb), dl, dh);
            bf8_to_f(*(const bf16x8*)(po + 128 + kb), o2l, o2h);
            bf8_to_f(*(const bf16x8*)(po + 256 + kb), o3l, o3h);
            a[t][kk] = cvt8(al + dl * o2l + o3l, ah + dh * o2h + o3h);
        }
    }
    float ewv[2][4];
#pragma unroll
    for (int t = 0; t < 2; ++t)
#pragma unroll
        for (int r = 0; r < 4; ++r)
            ewv[t][r] = ew[min(rbase + t * 16 + (lane >> 4) * 4 + r, NN - 1)];
#pragma unroll
    for (int c = 0; c < 4; ++c) {
        const int ct = ct0 + c;
        bf16x8 b[4];
#pragma unroll
        for (int kk = 0; kk < 4; ++kk)
            b[kk] = *(const bf16x8*)(Wpk + ((size_t)(ct * 4 + kk) * 64 + lane) * 8);
        f32x4 acc0 = {0.f, 0.f, 0.f, 0.f}, acc1 = {0.f, 0.f, 0.f, 0.f};
#pragma unroll
        for (int kk = 0; kk < 4; ++kk) {
            acc0 = __builtin_amdgcn_mfma_f32_16x16x32_bf16(a[0][kk], b[kk], acc0, 0, 0, 0);
            acc1 = __builtin_amdgcn_mfma_f32_16x16x32_bf16(a[1][kk], b[kk], acc1, 0, 0, 0);
        }
        const int col = ct * 16 + rlo;
        const float bv = bfco[col];
#pragma unroll
        for (int r = 0; r < 4; ++r) {
            int row0 = rbase + (lane >> 4) * 4 + r;
            if (row0 < NN)
                outx[(size_t)row0 * 128 + col] =
                    h1[(size_t)row0 * 384 + 256 + col] + (acc0[r] + bv) * ewv[0][r];
            int row1 = row0 + 16;
            if (row1 < NN)
                outx[(size_t)row1 * 128 + col] =
                    h1[(size_t)row1 * 384 + 256 + col] + (acc1[r] + bv) * ewv[1][r];
        }
    }
}

// ---------------- LN: dvn(bf16) = LN(v3p*o1 + agg) ; one row per wave -----------------
__global__ __launch_bounds__(256) void outvec_ln(const ushort_t* __restrict__ v3p,
        const ushort_t* __restrict__ o, const ushort_t* __restrict__ agg,
        const float* __restrict__ ln_scale, const float* __restrict__ ln_bias,
        ushort_t* __restrict__ dvn) {
    const int tid = threadIdx.x;              // 256 = 4 rows x 64 lanes
    const int c2 = tid & 63;
    const int row = blockIdx.x * 4 + (tid >> 6);
    const int n = row / 3;
    unsigned uv3 = *(const unsigned*)(v3p + (size_t)row * 128 + 2 * c2);
    unsigned uo1 = *(const unsigned*)(o + (size_t)n * 384 + 2 * c2);
    unsigned uag = *(const unsigned*)(agg + (size_t)row * 128 + 2 * c2);
    float dv0 = fmaf(bf2f((unsigned short)uv3), bf2f((unsigned short)uo1),
                     bf2f((unsigned short)uag));
    float dv1 = fmaf(bf2f((unsigned short)(uv3 >> 16)), bf2f((unsigned short)(uo1 >> 16)),
                     bf2f((unsigned short)(uag >> 16)));
    float s = dv0 + dv1;
    float s2 = fmaf(dv0, dv0, dv1 * dv1);
#pragma unroll
    for (int d = 1; d < 64; d <<= 1) {
        s += __shfl_xor(s, d, 64);
        s2 += __shfl_xor(s2, d, 64);
    }
    float mu = s * (1.f / 128.f);
    float rstd = rsqrtf(s2 * (1.f / 128.f) - mu * mu + 1e-5f);
    float r0 = fmaf((dv0 - mu) * rstd, ln_scale[2 * c2], ln_bias[2 * c2]);
    float r1 = fmaf((dv1 - mu) * rstd, ln_scale[2 * c2 + 1], ln_bias[2 * c2 + 1]);
    *(unsigned*)(dvn + (size_t)row * 128 + 2 * c2) = pack2(r0, r1);
}

extern "C" void kernel_launch(void* const* d_in, const int* in_sizes, int n_in,
                              void* d_out, int out_size, void* d_ws, size_t ws_size,
                              hipStream_t stream) {
    const float* x          = (const float*)d_in[0];
    const float* vec        = (const float*)d_in[1];
    const float* edge_vec   = (const float*)d_in[2];
    const float* edge_weight= (const float*)d_in[3];
    const float* W_fc1      = (const float*)d_in[4];
    const float* W_fcv      = (const float*)d_in[5];
    const float* b_fcv      = (const float*)d_in[6];
    const float* W_fco      = (const float*)d_in[7];
    const float* b_fco      = (const float*)d_in[8];
    const float* W_out      = (const float*)d_in[9];
    const float* W_vecproj  = (const float*)d_in[10];
    const float* W_equiv    = (const float*)d_in[11];
    const float* ln_scale   = (const float*)d_in[12];
    const float* ln_bias    = (const float*)d_in[13];
    const int*   edge_index = (const int*)d_in[14];

    float* out_x   = (float*)d_out;
    float* out_vec = out_x + (size_t)NN * DIM;
    ushort_t* Pb = (ushort_t*)d_out;           // N x 512 bf16, alias (dead before out writes)

    float* ws   = (float*)d_ws;
    float* h1   = ws;                                   // N*384 f32
    float* pv   = h1 + 11520000;                        // N*384 f32
    ushort_t* att_b  = (ushort_t*)(pv + 11520000);      // N*128 bf16
    ushort_t* vdot_b = att_b + 3840000;                 // N*128 bf16
    ushort_t* o_b    = vdot_b + 3840000;                // N*384 bf16
    ushort_t* agg_b  = o_b + 11520000;                  // 3N*128 bf16
    ushort_t* v3p_b  = agg_b + 11520000;                // 3N*128 bf16
    float* kvz  = (float*)(v3p_b + 11520000);           // 2176 f32
    // aliases (stream-ordered dead ranges):
    ushort_t* vp12_b = o_b;                             // 3N*256 bf16 spans o_b..agg_b
    float* slab = (float*)o_b;                          // KVB*2176 f32, dead before vp_gemm
    ushort_t* dvn_b = (ushort_t*)pv;                    // 3N*128 bf16, pv dead by then
    int* cnt    = (int*)(kvz + 2176);                   // N
    int* off    = cnt + NN;                             // N+1
    int* pos    = off + NN + 1;                         // N
    size_t soff = ((size_t)(pos + NN - (int*)ws) + 3) & ~(size_t)3;    // 16B align
    int4* sorted4 = (int4*)((int*)ws + soff);           // E * 16B
    short* Wpk  = (short*)((int*)ws + soff + (size_t)4 * EE);          // 448 frags
    short* pk_fc1  = Wpk;
    short* pk_fcv  = Wpk + 96 * 512;
    short* pk_wout = Wpk + 192 * 512;
    short* pk_vp   = Wpk + 288 * 512;          // unified 384-col vecproj (96 frags)
    short* pk_fco  = Wpk + 384 * 512;
    short* pk_weq  = Wpk + 416 * 512;

    hipMemsetAsync(cnt, 0, NN * sizeof(int), stream);

    pack_all<<<112, 256, 0, stream>>>(W_fc1, W_fcv, W_out, W_vecproj, W_fco, W_equiv, Wpk);

    // CSR build (depends only on edge_index / edge_vec)
    hist_kernel<<<(EE + 255) / 256, 256, 0, stream>>>(edge_index, cnt);
    scan_kernel<<<1, 1024, 0, stream>>>(cnt, off, pos);
    scatter_kernel<<<(EE + 255) / 256, 256, 0, stream>>>(edge_index, edge_vec, pos, sorted4);

    const int gN = (NN + 127) / 128;           // 235
    const int g3N = (3 * NN + 127) / 128;      // 704
    mfma_gemm<384, 8, false, float, float><<<dim3(gN, 3), 256, 0, stream>>>(x, pk_fc1, nullptr, h1, NN);
    mfma_gemm<384, 8, true, float, float><<<dim3(gN, 3), 256, 0, stream>>>(x, pk_fcv, b_fcv, pv, NN);
    kv_part<<<KVB, 256, 0, stream>>>(h1, pv, slab);
    kv_final<<<9, 256, 0, stream>>>(slab, kvz);
    attn_apply<<<NN / 8, 128, 0, stream>>>(h1, kvz, att_b);
    vp_gemm<<<dim3(g3N, 3), 256, 0, stream>>>(vec, pk_vp, vp12_b, v3p_b, 3 * NN);
    vecdot_reduce<<<NN / 8, 256, 0, stream>>>(vp12_b, vec, pv, vdot_b, Pb);
    mfma_gemm<384, 8, false, ushort_t, ushort_t><<<dim3(gN, 3), 256, 0, stream>>>(att_b, pk_wout, nullptr, o_b, NN);
    edge_agg_kernel<<<NN, 256, 0, stream>>>(off, sorted4, Pb, agg_b);
    outx_mfma<<<dim3(gN, 2), 256, 0, stream>>>(att_b, vdot_b, o_b, pk_fco, b_fco, h1, edge_weight, out_x);
    outvec_ln<<<(3 * NN) / 4, 256, 0, stream>>>(v3p_b, o_b, agg_b, ln_scale, ln_bias, dvn_b);
    mfma_gemm<128, 4, false, ushort_t, float><<<dim3(g3N, 2), 256, 0, stream>>>(dvn_b, pk_weq, nullptr, out_vec, 3 * NN);
}

// Round 11
// 399.416 us; speedup vs baseline: 1.1736x; 1.1177x over previous
//
#include <hip/hip_runtime.h>
#include <math.h>

#define NN 30000
#define EE 480000
#define DIM 128
#define KVB 512   // kv_part blocks

typedef __attribute__((ext_vector_type(8))) short bf16x8;
typedef __attribute__((ext_vector_type(8))) short s16x8;
typedef __attribute__((ext_vector_type(4))) short s16x4;
typedef __attribute__((ext_vector_type(4))) float f32x4;
typedef __attribute__((ext_vector_type(4))) float float4v;
typedef unsigned short ushort_t;

__device__ inline short f2bf(float f) {      // RNE f32 -> bf16
    union { float f; unsigned u; } v; v.f = f;
    unsigned u = v.u;
    u += 0x7fffu + ((u >> 16) & 1u);
    return (short)(u >> 16);
}
__device__ inline float bf2f(unsigned short u) {
    union { unsigned u; float f; } v; v.u = ((unsigned)u) << 16; return v.f;
}
__device__ inline unsigned pack2(float a, float b) {
    return (unsigned)(ushort_t)f2bf(a) | ((unsigned)(ushort_t)f2bf(b) << 16);
}

__device__ inline bf16x8 cvt8(float4v lo, float4v hi) {
    bf16x8 r;
    r[0] = f2bf(lo[0]); r[1] = f2bf(lo[1]); r[2] = f2bf(lo[2]); r[3] = f2bf(lo[3]);
    r[4] = f2bf(hi[0]); r[5] = f2bf(hi[1]); r[6] = f2bf(hi[2]); r[7] = f2bf(hi[3]);
    return r;
}
__device__ inline void bf8_to_f(bf16x8 v, float4v& lo, float4v& hi) {
#pragma unroll
    for (int i = 0; i < 4; ++i) {
        lo[i] = bf2f((unsigned short)v[i]);
        hi[i] = bf2f((unsigned short)v[4 + i]);
    }
}

// ---------------- weight pre-pack (fragment-major bf16) ----------------
__global__ void pack_all(const float* __restrict__ fc1, const float* __restrict__ fcv,
                         const float* __restrict__ wout, const float* __restrict__ wvp,
                         const float* __restrict__ fco, const float* __restrict__ weq,
                         short* __restrict__ Wpk) {
    int fid = blockIdx.x * 4 + (threadIdx.x >> 6);
    int lane = threadIdx.x & 63;
    const float* src; int Nsrc, c0, f;
    if (fid < 96)       { src = fc1;  Nsrc = 384; c0 = 0;   f = fid; }
    else if (fid < 192) { src = fcv;  Nsrc = 384; c0 = 0;   f = fid - 96; }
    else if (fid < 288) { src = wout; Nsrc = 384; c0 = 0;   f = fid - 192; }
    else if (fid < 352) { src = wvp;  Nsrc = 384; c0 = 0;   f = fid - 288; }
    else if (fid < 384) { src = wvp;  Nsrc = 384; c0 = 256; f = fid - 352; }
    else if (fid < 416) { src = fco;  Nsrc = 128; c0 = 0;   f = fid - 384; }
    else                { src = weq;  Nsrc = 128; c0 = 0;   f = fid - 416; }
    int ct = f >> 2, kk = f & 3;
    int k0 = kk * 32 + (lane >> 4) * 8;
    int col = c0 + ct * 16 + (lane & 15);
    bf16x8 v;
#pragma unroll
    for (int i = 0; i < 8; ++i) v[i] = f2bf(src[(size_t)(k0 + i) * Nsrc + col]);
    *(bf16x8*)(Wpk + ((size_t)fid * 64 + lane) * 8) = v;
}

// ---------------- fused x GEMM: y<3 -> h1 cols, y>=3 -> pv cols (bf16 out) ----------------
__global__ __launch_bounds__(256) void x_gemm(const float* __restrict__ in,
        const short* __restrict__ Wpk, const float* __restrict__ bfcv,
        ushort_t* __restrict__ h1, ushort_t* __restrict__ pv, int nrows) {
    const int lane = threadIdx.x & 63;
    const int wid = threadIdx.x >> 6;
    const int rbase = blockIdx.x * 128 + wid * 32;
    if (rbase >= nrows) return;
    const bool isPv = blockIdx.y >= 3;
    const int ct0 = (blockIdx.y - (isPv ? 3 : 0)) * 8;
    const short* W = Wpk + (isPv ? 96 * 512 : 0);
    ushort_t* out = isPv ? pv : h1;
    const int rlo = lane & 15, khi = (lane >> 4) * 8;
    bf16x8 a[2][4];
#pragma unroll
    for (int t = 0; t < 2; ++t) {
        int row = min(rbase + t * 16 + rlo, nrows - 1);
        const float* rp = in + (size_t)row * 128 + khi;
#pragma unroll
        for (int kk = 0; kk < 4; ++kk) {
            float4v lo = *(const float4v*)(rp + kk * 32);
            float4v hi = *(const float4v*)(rp + kk * 32 + 4);
            a[t][kk] = cvt8(lo, hi);
        }
    }
#pragma unroll
    for (int c = 0; c < 8; ++c) {
        const int ct = ct0 + c;
        bf16x8 b[4];
#pragma unroll
        for (int kk = 0; kk < 4; ++kk)
            b[kk] = *(const bf16x8*)(W + ((size_t)(ct * 4 + kk) * 64 + lane) * 8);
        f32x4 acc0 = {0.f, 0.f, 0.f, 0.f}, acc1 = {0.f, 0.f, 0.f, 0.f};
#pragma unroll
        for (int kk = 0; kk < 4; ++kk) {
            acc0 = __builtin_amdgcn_mfma_f32_16x16x32_bf16(a[0][kk], b[kk], acc0, 0, 0, 0);
            acc1 = __builtin_amdgcn_mfma_f32_16x16x32_bf16(a[1][kk], b[kk], acc1, 0, 0, 0);
        }
        const int col = ct * 16 + rlo;
        const float bv = isPv ? bfcv[col] : 0.f;
#pragma unroll
        for (int r = 0; r < 4; ++r) {
            int row0 = rbase + (lane >> 4) * 4 + r;
            int row1 = row0 + 16;
            if (row0 < nrows) out[(size_t)row0 * 384 + col] = (ushort_t)f2bf(acc0[r] + bv);
            if (row1 < nrows) out[(size_t)row1 * 384 + col] = (ushort_t)f2bf(acc1[r] + bv);
        }
    }
}

// ---------------- generic MFMA GEMM with col-tile blocking (blockIdx.y) -------------------
template<int COLS, int CT_PER, bool BIAS, typename InT, typename OutT>
__global__ __launch_bounds__(256) void mfma_gemm(const InT* __restrict__ in,
        const short* __restrict__ Wpk, const float* __restrict__ bias,
        OutT* __restrict__ out, int nrows) {
    const int lane = threadIdx.x & 63;
    const int wid = threadIdx.x >> 6;
    const int rbase = blockIdx.x * 128 + wid * 32;
    if (rbase >= nrows) return;
    const int ct0 = blockIdx.y * CT_PER;
    const int rlo = lane & 15, khi = (lane >> 4) * 8;
    bf16x8 a[2][4];
#pragma unroll
    for (int t = 0; t < 2; ++t) {
        int row = min(rbase + t * 16 + rlo, nrows - 1);
        const InT* rp = in + (size_t)row * 128 + khi;
#pragma unroll
        for (int kk = 0; kk < 4; ++kk) {
            if constexpr (sizeof(InT) == 4) {
                float4v lo = *(const float4v*)(rp + kk * 32);
                float4v hi = *(const float4v*)(rp + kk * 32 + 4);
                a[t][kk] = cvt8(lo, hi);
            } else {
                a[t][kk] = *(const bf16x8*)(rp + kk * 32);
            }
        }
    }
#pragma unroll
    for (int c = 0; c < CT_PER; ++c) {
        const int ct = ct0 + c;
        bf16x8 b[4];
#pragma unroll
        for (int kk = 0; kk < 4; ++kk)
            b[kk] = *(const bf16x8*)(Wpk + ((size_t)(ct * 4 + kk) * 64 + lane) * 8);
        f32x4 acc0 = {0.f, 0.f, 0.f, 0.f}, acc1 = {0.f, 0.f, 0.f, 0.f};
#pragma unroll
        for (int kk = 0; kk < 4; ++kk) {
            acc0 = __builtin_amdgcn_mfma_f32_16x16x32_bf16(a[0][kk], b[kk], acc0, 0, 0, 0);
            acc1 = __builtin_amdgcn_mfma_f32_16x16x32_bf16(a[1][kk], b[kk], acc1, 0, 0, 0);
        }
        const int col = ct * 16 + rlo;
        const float bv = BIAS ? bias[col] : 0.f;
#pragma unroll
        for (int r = 0; r < 4; ++r) {
            int row0 = rbase + (lane >> 4) * 4 + r;
            int row1 = row0 + 16;
            if constexpr (sizeof(OutT) == 4) {
                if (row0 < nrows) out[(size_t)row0 * COLS + col] = acc0[r] + bv;
                if (row1 < nrows) out[(size_t)row1 * COLS + col] = acc1[r] + bv;
            } else {
                if (row0 < nrows) out[(size_t)row0 * COLS + col] = (OutT)f2bf(acc0[r] + bv);
                if (row1 < nrows) out[(size_t)row1 * COLS + col] = (OutT)f2bf(acc1[r] + bv);
            }
        }
    }
}

// ---------------- vecproj GEMM (all 24 col-tiles, single y): vp12 + v3p bf16 ----------------
__global__ __launch_bounds__(256) void vp_gemm(const float* __restrict__ in,
        const short* __restrict__ Wpk, ushort_t* __restrict__ vp12,
        ushort_t* __restrict__ v3p, int nrows) {
    const int lane = threadIdx.x & 63;
    const int wid = threadIdx.x >> 6;
    const int rbase = blockIdx.x * 128 + wid * 32;
    if (rbase >= nrows) return;
    const int rlo = lane & 15, khi = (lane >> 4) * 8;
    bf16x8 a[2][4];
#pragma unroll
    for (int t = 0; t < 2; ++t) {
        int row = min(rbase + t * 16 + rlo, nrows - 1);
        const float* rp = in + (size_t)row * 128 + khi;
#pragma unroll
        for (int kk = 0; kk < 4; ++kk) {
            float4v lo = *(const float4v*)(rp + kk * 32);
            float4v hi = *(const float4v*)(rp + kk * 32 + 4);
            a[t][kk] = cvt8(lo, hi);
        }
    }
    for (int ct = 0; ct < 24; ++ct) {
        bf16x8 b[4];
#pragma unroll
        for (int kk = 0; kk < 4; ++kk)
            b[kk] = *(const bf16x8*)(Wpk + ((size_t)(ct * 4 + kk) * 64 + lane) * 8);
        f32x4 acc0 = {0.f, 0.f, 0.f, 0.f}, acc1 = {0.f, 0.f, 0.f, 0.f};
#pragma unroll
        for (int kk = 0; kk < 4; ++kk) {
            acc0 = __builtin_amdgcn_mfma_f32_16x16x32_bf16(a[0][kk], b[kk], acc0, 0, 0, 0);
            acc1 = __builtin_amdgcn_mfma_f32_16x16x32_bf16(a[1][kk], b[kk], acc1, 0, 0, 0);
        }
        const int col = ct * 16 + rlo;
#pragma unroll
        for (int r = 0; r < 4; ++r) {
            int row0 = rbase + (lane >> 4) * 4 + r;
            int row1 = row0 + 16;
            if (col < 256) {
                if (row0 < nrows) vp12[(size_t)row0 * 256 + col] = (ushort_t)f2bf(acc0[r]);
                if (row1 < nrows) vp12[(size_t)row1 * 256 + col] = (ushort_t)f2bf(acc1[r]);
            } else {
                if (row0 < nrows) v3p[(size_t)row0 * 128 + col - 256] = (ushort_t)f2bf(acc0[r]);
                if (row1 < nrows) v3p[(size_t)row1 * 128 + col - 256] = (ushort_t)f2bf(acc1[r]);
            }
        }
    }
}

// ---------------- kv stage 1 (bf16 in): per-block partials, no atomics ----------------
__global__ __launch_bounds__(256) void kv_part(const ushort_t* __restrict__ h1,
        const ushort_t* __restrict__ pv, float* __restrict__ slab) {
    __shared__ float kf_s[8][DIM];
    __shared__ float v_s[8][DIM];
    const int tid = threadIdx.x;              // 256
    const int rpb = (NN + KVB - 1) / KVB;     // 59
    const int n0 = blockIdx.x * rpb;
    const int n1 = min(n0 + rpb, NN);
    const int base = tid * 8;
    const int hf = base >> 4;
    const int h = hf >> 4;
    const int d0 = base & 15;
    const int lr = tid >> 5;
    const int lg = tid & 31;
    const bool isK = lg < 16;
    const int le = (lg & 15) * 8;
    float acc[8];
#pragma unroll
    for (int i = 0; i < 8; ++i) acc[i] = 0.f;
    float zacc = 0.f;
    s16x8 praw = {0,0,0,0,0,0,0,0};
    bool pvalid = false;
    {
        int n = n0 + lr;
        pvalid = n < n1;
        if (pvalid) {
            const ushort_t* src = isK ? (h1 + (size_t)n * 384 + 128 + le)
                                      : (pv + (size_t)n * 384 + le);
            praw = *(const s16x8*)src;
        }
    }
    for (int nt = n0; nt < n1; nt += 8) {
        __syncthreads();
        float v8[8];
#pragma unroll
        for (int i = 0; i < 8; ++i) v8[i] = pvalid ? bf2f((unsigned short)praw[i]) : 0.f;
        if (pvalid && isK) {
#pragma unroll
            for (int i = 0; i < 8; ++i) v8[i] = v8[i] > 0.f ? v8[i] + 1.f : expf(v8[i]);
        }
        float* dst = (isK ? kf_s[lr] : v_s[lr]) + le;
#pragma unroll
        for (int i = 0; i < 8; ++i) dst[i] = v8[i];
        __syncthreads();
        {
            int n = nt + 8 + lr;
            pvalid = n < n1;
            if (pvalid) {
                const ushort_t* src = isK ? (h1 + (size_t)n * 384 + 128 + le)
                                          : (pv + (size_t)n * 384 + le);
                praw = *(const s16x8*)src;
            }
        }
#pragma unroll
        for (int r = 0; r < 8; ++r) {
            float kfv = kf_s[r][hf];
#pragma unroll
            for (int i = 0; i < 8; ++i) acc[i] = fmaf(kfv, v_s[r][h * 16 + d0 + i], acc[i]);
            if (tid < 128) zacc += kf_s[r][tid];
        }
    }
    float* row = slab + (size_t)blockIdx.x * 2176;
#pragma unroll
    for (int i = 0; i < 8; ++i) row[base + i] = acc[i];
    if (tid < 128) row[2048 + tid] = zacc;
}

// ---------------- kv stage 2: kvz[i] = sum_b slab[b][i] ----------------
__global__ void kv_final(const float* __restrict__ slab, float* __restrict__ kvz) {
    int i = blockIdx.x * 256 + threadIdx.x;
    if (i >= 2176) return;
    float a[8];
#pragma unroll
    for (int j = 0; j < 8; ++j) a[j] = 0.f;
    for (int b = 0; b < KVB; b += 8) {
#pragma unroll
        for (int j = 0; j < 8; ++j) a[j] += slab[(size_t)(b + j) * 2176 + i];
    }
    kvz[i] = ((a[0] + a[1]) + (a[2] + a[3])) + ((a[4] + a[5]) + (a[6] + a[7]));
}

// ---------------- att(bf16)[n,h*16+d] = (qf . kv) / (qf . z + 1e-6) ----------------
__global__ void attn_apply(const ushort_t* __restrict__ h1, const float* __restrict__ kvz,
                           ushort_t* __restrict__ att) {
    __shared__ float kv_s[8 * 16 * 17];
    __shared__ float z_s[DIM];
    __shared__ float qf_s[8][DIM];
    const int tid = threadIdx.x;              // 128
    const int n0 = blockIdx.x * 8;
    for (int i = tid; i < 2048; i += 128) {
        int hf = i >> 4, d = i & 15;
        kv_s[hf * 17 + d] = kvz[i];
    }
    z_s[tid] = kvz[2048 + tid];
#pragma unroll
    for (int r = 0; r < 8; ++r) {
        float qv = bf2f(h1[(size_t)(n0 + r) * 384 + tid]);
        qf_s[r][tid] = qv > 0.f ? qv + 1.f : expf(qv);
    }
    __syncthreads();
    const int h = tid >> 4, d = tid & 15;
#pragma unroll
    for (int r = 0; r < 8; ++r) {
        float num = 0.f, den = 0.f;
#pragma unroll
        for (int f = 0; f < 16; ++f) {
            float q = qf_s[r][h * 16 + f];
            num = fmaf(q, kv_s[(h * 16 + f) * 17 + d], num);
            den = fmaf(q, z_s[h * 16 + f], den);
        }
        att[(size_t)(n0 + r) * DIM + tid] = (ushort_t)f2bf(num / (den + 1e-6f));
    }
}

// ---------------- vdot(bf16) + P-pack, col-pair vectorized (pv bf16) ----------------
__global__ __launch_bounds__(256) void vecdot_reduce(const ushort_t* __restrict__ vp12,
        const float* __restrict__ vec, const ushort_t* __restrict__ pv,
        ushort_t* __restrict__ vdot, ushort_t* __restrict__ P) {
    const int tid = threadIdx.x;              // 256
    const int c2 = tid & 63;                  // cols {2c2, 2c2+1}
    const int sub = tid >> 6;                 // 0..3
    const int n0 = blockIdx.x * 8;
#pragma unroll
    for (int rr = 0; rr < 2; ++rr) {
        const int n = n0 + sub + rr * 4;
        float a0 = 0.f, a1 = 0.f;
#pragma unroll
        for (int c = 0; c < 3; ++c) {
            unsigned u1 = *(const unsigned*)(vp12 + (size_t)(3 * n + c) * 256 + 2 * c2);
            unsigned u2 = *(const unsigned*)(vp12 + (size_t)(3 * n + c) * 256 + 128 + 2 * c2);
            a0 = fmaf(bf2f((unsigned short)u1), bf2f((unsigned short)u2), a0);
            a1 = fmaf(bf2f((unsigned short)(u1 >> 16)), bf2f((unsigned short)(u2 >> 16)), a1);
        }
        *(unsigned*)(vdot + (size_t)n * 128 + 2 * c2) = pack2(a0, a1);
        unsigned uv1 = *(const unsigned*)(pv + (size_t)n * 384 + 128 + 2 * c2);
        unsigned uv2 = *(const unsigned*)(pv + (size_t)n * 384 + 256 + 2 * c2);
        float v1x = bf2f((unsigned short)uv1), v1y = bf2f((unsigned short)(uv1 >> 16));
        s16x8 pk;
        pk[0] = (short)(ushort_t)(uv2 & 0xffffu);
        pk[4] = (short)(ushort_t)(uv2 >> 16);
#pragma unroll
        for (int c = 0; c < 3; ++c) {
            float2 vc = *(const float2*)(vec + ((size_t)n * 3 + c) * 128 + 2 * c2);
            pk[1 + c] = f2bf(vc.x * v1x);
            pk[5 + c] = f2bf(vc.y * v1y);
        }
        *(s16x8*)(P + (size_t)n * 512 + (size_t)c2 * 8) = pk;
    }
}

// ---------------- edge CSR build ----------------
__global__ void hist_kernel(const int* __restrict__ eidx, int* __restrict__ cnt) {
    int e = blockIdx.x * 256 + threadIdx.x;
    if (e < EE) atomicAdd(&cnt[eidx[EE + e]], 1);
}

__global__ void scan_kernel(const int* __restrict__ cnt, int* __restrict__ off,
                            int* __restrict__ pos) {
    __shared__ int wsum[16];
    const int tid = threadIdx.x;              // 1024
    const int lane = tid & 63, wv = tid >> 6;
    const int PER = 30;
    const int base = tid * PER;
    int local[PER];
    int s = 0;
#pragma unroll
    for (int i = 0; i < PER; ++i) {
        int idx = base + i;
        int c = (idx < NN) ? cnt[idx] : 0;
        local[i] = s;
        s += c;
    }
    int incl = s;
#pragma unroll
    for (int d = 1; d < 64; d <<= 1) {
        int v = __shfl_up(incl, d, 64);
        if (lane >= d) incl += v;
    }
    if (lane == 63) wsum[wv] = incl;
    __syncthreads();
    if (wv == 0 && lane < 16) {
        int v = wsum[lane];
        int iv = v;
#pragma unroll
        for (int d = 1; d < 16; d <<= 1) {
            int u = __shfl_up(iv, d, 16);
            if (lane >= d) iv += u;
        }
        wsum[lane] = iv - v;
    }
    __syncthreads();
    const int carry = wsum[wv] + (incl - s);
#pragma unroll
    for (int i = 0; i < PER; ++i) {
        int idx = base + i;
        if (idx < NN) {
            int v = carry + local[i];
            off[idx] = v;
            pos[idx] = v;
        }
    }
    if (tid == 1023) off[NN] = wsum[15] + incl;
}

// scatter one 16B record per edge: {src, ev0, ev1, ev2}
__global__ void scatter_kernel(const int* __restrict__ eidx, const float* __restrict__ evec,
                               int* __restrict__ pos, int4* __restrict__ sorted4) {
    int e = blockIdx.x * 256 + threadIdx.x;
    if (e >= EE) return;
    int dst = eidx[EE + e];
    int src = eidx[e];
    float e0 = evec[(size_t)e * 3 + 0];
    float e1 = evec[(size_t)e * 3 + 1];
    float e2 = evec[(size_t)e * 3 + 2];
    int p = atomicAdd(&pos[dst], 1);
    sorted4[p] = make_int4(src, __float_as_int(e0), __float_as_int(e1), __float_as_int(e2));
}

// ---------------- segmented gather-reduce: one block (2 groups x 128 lanes) per dst -------
__global__ __launch_bounds__(256) void edge_agg_kernel(
        const int* __restrict__ off, const int4* __restrict__ sorted4,
        const ushort_t* __restrict__ P, ushort_t* __restrict__ agg) {
    __shared__ int srcs[128];
    __shared__ float evs[3][128];
    __shared__ float part[3][128];
    const int dst = blockIdx.x;
    const int tid = threadIdx.x;              // 256
    const int g = tid >> 7, o = tid & 127;
    const int j0 = off[dst], j1 = off[dst + 1];
    float a0 = 0.f, a1 = 0.f, a2 = 0.f;
    for (int jt = j0; jt < j1; jt += 128) {
        const int m = min(128, j1 - jt);
        if (tid < m) {
            int4 w = sorted4[jt + tid];
            srcs[tid] = w.x;
            evs[0][tid] = __int_as_float(w.y);
            evs[1][tid] = __int_as_float(w.z);
            evs[2][tid] = __int_as_float(w.w);
        }
        __syncthreads();
        int jj = g;
        for (; jj + 14 < m; jj += 16) {        // 8 edges per group-iteration
            s16x4 pk[8];
#pragma unroll
            for (int u = 0; u < 8; ++u)
                pk[u] = *(const s16x4*)(P + (size_t)srcs[jj + 2 * u] * 512 + o * 4);
#pragma unroll
            for (int u = 0; u < 8; ++u) {
                int e = jj + 2 * u;
                float v2 = bf2f((unsigned short)pk[u][0]);
                a0 += fmaf(evs[0][e], v2, bf2f((unsigned short)pk[u][1]));
                a1 += fmaf(evs[1][e], v2, bf2f((unsigned short)pk[u][2]));
                a2 += fmaf(evs[2][e], v2, bf2f((unsigned short)pk[u][3]));
            }
        }
        for (; jj < m; jj += 2) {
            s16x4 pk = *(const s16x4*)(P + (size_t)srcs[jj] * 512 + o * 4);
            float v2 = bf2f((unsigned short)pk[0]);
            a0 += fmaf(evs[0][jj], v2, bf2f((unsigned short)pk[1]));
            a1 += fmaf(evs[1][jj], v2, bf2f((unsigned short)pk[2]));
            a2 += fmaf(evs[2][jj], v2, bf2f((unsigned short)pk[3]));
        }
        __syncthreads();
    }
    if (g == 1) { part[0][o] = a0; part[1][o] = a1; part[2][o] = a2; }
    __syncthreads();
    if (g == 0) {
        a0 += part[0][o]; a1 += part[1][o]; a2 += part[2][o];
        agg[((size_t)dst * 3 + 0) * DIM + o] = (ushort_t)f2bf(a0);
        agg[((size_t)dst * 3 + 1) * DIM + o] = (ushort_t)f2bf(a1);
        agg[((size_t)dst * 3 + 2) * DIM + o] = (ushort_t)f2bf(a2);
    }
}

// ---------------- out_x = non_att + ((att + vdot*o2 + o3) @ W_fco + b_fco)*ew (MFMA) ------
__global__ __launch_bounds__(256) void outx_mfma(const ushort_t* __restrict__ att,
        const ushort_t* __restrict__ vdot, const ushort_t* __restrict__ o,
        const short* __restrict__ Wpk, const float* __restrict__ bfco,
        const ushort_t* __restrict__ h1, const float* __restrict__ ew,
        float* __restrict__ outx) {
    const int lane = threadIdx.x & 63;
    const int wid = threadIdx.x >> 6;
    const int rbase = blockIdx.x * 128 + wid * 32;
    if (rbase >= NN) return;
    const int ct0 = blockIdx.y * 4;
    const int rlo = lane & 15, khi = (lane >> 4) * 8;
    bf16x8 a[2][4];
#pragma unroll
    for (int t = 0; t < 2; ++t) {
        int row = min(rbase + t * 16 + rlo, NN - 1);
        const ushort_t* pa = att + (size_t)row * 128 + khi;
        const ushort_t* pd = vdot + (size_t)row * 128 + khi;
        const ushort_t* po = o + (size_t)row * 384 + khi;
#pragma unroll
        for (int kk = 0; kk < 4; ++kk) {
            int kb = kk * 32;
            float4v al, ah, dl, dh, o2l, o2h, o3l, o3h;
            bf8_to_f(*(const bf16x8*)(pa + kb), al, ah);
            bf8_to_f(*(const bf16x8*)(pd + kb), dl, dh);
            bf8_to_f(*(const bf16x8*)(po + 128 + kb), o2l, o2h);
            bf8_to_f(*(const bf16x8*)(po + 256 + kb), o3l, o3h);
            a[t][kk] = cvt8(al + dl * o2l + o3l, ah + dh * o2h + o3h);
        }
    }
    float ewv[2][4];
#pragma unroll
    for (int t = 0; t < 2; ++t)
#pragma unroll
        for (int r = 0; r < 4; ++r)
            ewv[t][r] = ew[min(rbase + t * 16 + (lane >> 4) * 4 + r, NN - 1)];
#pragma unroll
    for (int c = 0; c < 4; ++c) {
        const int ct = ct0 + c;
        bf16x8 b[4];
#pragma unroll
        for (int kk = 0; kk < 4; ++kk)
            b[kk] = *(const bf16x8*)(Wpk + ((size_t)(ct * 4 + kk) * 64 + lane) * 8);
        f32x4 acc0 = {0.f, 0.f, 0.f, 0.f}, acc1 = {0.f, 0.f, 0.f, 0.f};
#pragma unroll
        for (int kk = 0; kk < 4; ++kk) {
            acc0 = __builtin_amdgcn_mfma_f32_16x16x32_bf16(a[0][kk], b[kk], acc0, 0, 0, 0);
            acc1 = __builtin_amdgcn_mfma_f32_16x16x32_bf16(a[1][kk], b[kk], acc1, 0, 0, 0);
        }
        const int col = ct * 16 + rlo;
        const float bv = bfco[col];
#pragma unroll
        for (int r = 0; r < 4; ++r) {
            int row0 = rbase + (lane >> 4) * 4 + r;
            if (row0 < NN)
                outx[(size_t)row0 * 128 + col] =
                    bf2f(h1[(size_t)row0 * 384 + 256 + col]) + (acc0[r] + bv) * ewv[0][r];
            int row1 = row0 + 16;
            if (row1 < NN)
                outx[(size_t)row1 * 128 + col] =
                    bf2f(h1[(size_t)row1 * 384 + 256 + col]) + (acc1[r] + bv) * ewv[1][r];
        }
    }
}

// ---------------- LN: dvn(bf16) = LN(v3p*o1 + agg) ; one row per wave -----------------
__global__ __launch_bounds__(256) void outvec_ln(const ushort_t* __restrict__ v3p,
        const ushort_t* __restrict__ o, const ushort_t* __restrict__ agg,
        const float* __restrict__ ln_scale, const float* __restrict__ ln_bias,
        ushort_t* __restrict__ dvn) {
    const int tid = threadIdx.x;              // 256 = 4 rows x 64 lanes
    const int c2 = tid & 63;
    const int row = blockIdx.x * 4 + (tid >> 6);
    const int n = row / 3;
    unsigned uv3 = *(const unsigned*)(v3p + (size_t)row * 128 + 2 * c2);
    unsigned uo1 = *(const unsigned*)(o + (size_t)n * 384 + 2 * c2);
    unsigned uag = *(const unsigned*)(agg + (size_t)row * 128 + 2 * c2);
    float dv0 = fmaf(bf2f((unsigned short)uv3), bf2f((unsigned short)uo1),
                     bf2f((unsigned short)uag));
    float dv1 = fmaf(bf2f((unsigned short)(uv3 >> 16)), bf2f((unsigned short)(uo1 >> 16)),
                     bf2f((unsigned short)(uag >> 16)));
    float s = dv0 + dv1;
    float s2 = fmaf(dv0, dv0, dv1 * dv1);
#pragma unroll
    for (int d = 1; d < 64; d <<= 1) {
        s += __shfl_xor(s, d, 64);
        s2 += __shfl_xor(s2, d, 64);
    }
    float mu = s * (1.f / 128.f);
    float rstd = rsqrtf(s2 * (1.f / 128.f) - mu * mu + 1e-5f);
    float r0 = fmaf((dv0 - mu) * rstd, ln_scale[2 * c2], ln_bias[2 * c2]);
    float r1 = fmaf((dv1 - mu) * rstd, ln_scale[2 * c2 + 1], ln_bias[2 * c2 + 1]);
    *(unsigned*)(dvn + (size_t)row * 128 + 2 * c2) = pack2(r0, r1);
}

extern "C" void kernel_launch(void* const* d_in, const int* in_sizes, int n_in,
                              void* d_out, int out_size, void* d_ws, size_t ws_size,
                              hipStream_t stream) {
    const float* x          = (const float*)d_in[0];
    const float* vec        = (const float*)d_in[1];
    const float* edge_vec   = (const float*)d_in[2];
    const float* edge_weight= (const float*)d_in[3];
    const float* W_fc1      = (const float*)d_in[4];
    const float* W_fcv      = (const float*)d_in[5];
    const float* b_fcv      = (const float*)d_in[6];
    const float* W_fco      = (const float*)d_in[7];
    const float* b_fco      = (const float*)d_in[8];
    const float* W_out      = (const float*)d_in[9];
    const float* W_vecproj  = (const float*)d_in[10];
    const float* W_equiv    = (const float*)d_in[11];
    const float* ln_scale   = (const float*)d_in[12];
    const float* ln_bias    = (const float*)d_in[13];
    const int*   edge_index = (const int*)d_in[14];

    float* out_x   = (float*)d_out;
    float* out_vec = out_x + (size_t)NN * DIM;
    ushort_t* Pb = (ushort_t*)d_out;           // N x 512 bf16, alias (dead before out writes)

    float* ws   = (float*)d_ws;
    ushort_t* h1_b   = (ushort_t*)ws;                   // N*384 bf16
    ushort_t* pv_b   = h1_b + 11520000;                 // N*384 bf16
    ushort_t* att_b  = pv_b + 11520000;                 // N*128 bf16
    ushort_t* vdot_b = att_b + 3840000;                 // N*128 bf16
    ushort_t* o_b    = vdot_b + 3840000;                // N*384 bf16
    ushort_t* agg_b  = o_b + 11520000;                  // 3N*128 bf16
    ushort_t* v3p_b  = agg_b + 11520000;                // 3N*128 bf16
    float* kvz  = (float*)(v3p_b + 11520000);           // 2176 f32
    // aliases (stream-ordered dead ranges):
    ushort_t* vp12_b = o_b;                             // 3N*256 bf16 spans o_b..agg_b
    float* slab = (float*)o_b;                          // KVB*2176 f32, dead before vp_gemm
    ushort_t* dvn_b = pv_b;                             // 3N*128 bf16, pv dead by then
    int* cnt    = (int*)(kvz + 2176);                   // N
    int* off    = cnt + NN;                             // N+1
    int* pos    = off + NN + 1;                         // N
    size_t soff = ((size_t)(pos + NN - (int*)ws) + 3) & ~(size_t)3;    // 16B align
    int4* sorted4 = (int4*)((int*)ws + soff);           // E * 16B
    short* Wpk  = (short*)((int*)ws + soff + (size_t)4 * EE);          // 448 frags
    short* pk_fc1  = Wpk;                      // fc1+fcv contiguous (192 frags)
    short* pk_wout = Wpk + 192 * 512;
    short* pk_vp   = Wpk + 288 * 512;          // unified 384-col vecproj (96 frags)
    short* pk_fco  = Wpk + 384 * 512;
    short* pk_weq  = Wpk + 416 * 512;

    hipMemsetAsync(cnt, 0, NN * sizeof(int), stream);

    pack_all<<<112, 256, 0, stream>>>(W_fc1, W_fcv, W_out, W_vecproj, W_fco, W_equiv, Wpk);

    // CSR build (depends only on edge_index / edge_vec)
    hist_kernel<<<(EE + 255) / 256, 256, 0, stream>>>(edge_index, cnt);
    scan_kernel<<<1, 1024, 0, stream>>>(cnt, off, pos);
    scatter_kernel<<<(EE + 255) / 256, 256, 0, stream>>>(edge_index, edge_vec, pos, sorted4);

    const int gN = (NN + 127) / 128;           // 235
    const int g3N = (3 * NN + 127) / 128;      // 704
    x_gemm<<<dim3(gN, 6), 256, 0, stream>>>(x, pk_fc1, b_fcv, h1_b, pv_b, NN);
    kv_part<<<KVB, 256, 0, stream>>>(h1_b, pv_b, slab);
    kv_final<<<9, 256, 0, stream>>>(slab, kvz);
    attn_apply<<<NN / 8, 128, 0, stream>>>(h1_b, kvz, att_b);
    vp_gemm<<<g3N, 256, 0, stream>>>(vec, pk_vp, vp12_b, v3p_b, 3 * NN);
    vecdot_reduce<<<NN / 8, 256, 0, stream>>>(vp12_b, vec, pv_b, vdot_b, Pb);
    mfma_gemm<384, 8, false, ushort_t, ushort_t><<<dim3(gN, 3), 256, 0, stream>>>(att_b, pk_wout, nullptr, o_b, NN);
    edge_agg_kernel<<<NN, 256, 0, stream>>>(off, sorted4, Pb, agg_b);
    outx_mfma<<<dim3(gN, 2), 256, 0, stream>>>(att_b, vdot_b, o_b, pk_fco, b_fco, h1_b, edge_weight, out_x);
    outvec_ln<<<(3 * NN) / 4, 256, 0, stream>>>(v3p_b, o_b, agg_b, ln_scale, ln_bias, dvn_b);
    mfma_gemm<128, 8, false, ushort_t, float><<<g3N, 256, 0, stream>>>(dvn_b, pk_weq, nullptr, out_vec, 3 * NN);
}

// Round 12
// 368.797 us; speedup vs baseline: 1.2710x; 1.0830x over previous
//
#include <hip/hip_runtime.h>
#include <math.h>

#define NN 30000
#define EE 480000
#define DIM 128
#define KVB 512   // kv_part blocks

typedef __attribute__((ext_vector_type(8))) short bf16x8;
typedef __attribute__((ext_vector_type(8))) short s16x8;
typedef __attribute__((ext_vector_type(4))) short s16x4;
typedef __attribute__((ext_vector_type(4))) float f32x4;
typedef __attribute__((ext_vector_type(4))) float float4v;
typedef unsigned short ushort_t;

__device__ inline short f2bf(float f) {      // RNE f32 -> bf16
    union { float f; unsigned u; } v; v.f = f;
    unsigned u = v.u;
    u += 0x7fffu + ((u >> 16) & 1u);
    return (short)(u >> 16);
}
__device__ inline float bf2f(unsigned short u) {
    union { unsigned u; float f; } v; v.u = ((unsigned)u) << 16; return v.f;
}
__device__ inline unsigned pack2(float a, float b) {
    return (unsigned)(ushort_t)f2bf(a) | ((unsigned)(ushort_t)f2bf(b) << 16);
}

__device__ inline bf16x8 cvt8(float4v lo, float4v hi) {
    bf16x8 r;
    r[0] = f2bf(lo[0]); r[1] = f2bf(lo[1]); r[2] = f2bf(lo[2]); r[3] = f2bf(lo[3]);
    r[4] = f2bf(hi[0]); r[5] = f2bf(hi[1]); r[6] = f2bf(hi[2]); r[7] = f2bf(hi[3]);
    return r;
}
__device__ inline void bf8_to_f(bf16x8 v, float4v& lo, float4v& hi) {
#pragma unroll
    for (int i = 0; i < 4; ++i) {
        lo[i] = bf2f((unsigned short)v[i]);
        hi[i] = bf2f((unsigned short)v[4 + i]);
    }
}

// ---------------- weight pre-pack (fragment-major bf16) ----------------
__global__ void pack_all(const float* __restrict__ fc1, const float* __restrict__ fcv,
                         const float* __restrict__ wout, const float* __restrict__ wvp,
                         const float* __restrict__ fco, const float* __restrict__ weq,
                         short* __restrict__ Wpk) {
    int fid = blockIdx.x * 4 + (threadIdx.x >> 6);
    int lane = threadIdx.x & 63;
    const float* src; int Nsrc, c0, f;
    if (fid < 96)       { src = fc1;  Nsrc = 384; c0 = 0;   f = fid; }
    else if (fid < 192) { src = fcv;  Nsrc = 384; c0 = 0;   f = fid - 96; }
    else if (fid < 288) { src = wout; Nsrc = 384; c0 = 0;   f = fid - 192; }
    else if (fid < 352) { src = wvp;  Nsrc = 384; c0 = 0;   f = fid - 288; }
    else if (fid < 384) { src = wvp;  Nsrc = 384; c0 = 256; f = fid - 352; }
    else if (fid < 416) { src = fco;  Nsrc = 128; c0 = 0;   f = fid - 384; }
    else                { src = weq;  Nsrc = 128; c0 = 0;   f = fid - 416; }
    int ct = f >> 2, kk = f & 3;
    int k0 = kk * 32 + (lane >> 4) * 8;
    int col = c0 + ct * 16 + (lane & 15);
    bf16x8 v;
#pragma unroll
    for (int i = 0; i < 8; ++i) v[i] = f2bf(src[(size_t)(k0 + i) * Nsrc + col]);
    *(bf16x8*)(Wpk + ((size_t)fid * 64 + lane) * 8) = v;
}

// ---------------- fused x GEMM (dual output per block): 8 h1-tiles + 8 pv-tiles -----------
__global__ __launch_bounds__(256) void x_gemm(const float* __restrict__ in,
        const short* __restrict__ Wpk, const float* __restrict__ bfcv,
        ushort_t* __restrict__ h1, ushort_t* __restrict__ pv, int nrows) {
    const int lane = threadIdx.x & 63;
    const int wid = threadIdx.x >> 6;
    const int rbase = blockIdx.x * 128 + wid * 32;
    if (rbase >= nrows) return;
    const int ct0 = blockIdx.y * 8;
    const int rlo = lane & 15, khi = (lane >> 4) * 8;
    bf16x8 a[2][4];
#pragma unroll
    for (int t = 0; t < 2; ++t) {
        int row = min(rbase + t * 16 + rlo, nrows - 1);
        const float* rp = in + (size_t)row * 128 + khi;
#pragma unroll
        for (int kk = 0; kk < 4; ++kk) {
            float4v lo = *(const float4v*)(rp + kk * 32);
            float4v hi = *(const float4v*)(rp + kk * 32 + 4);
            a[t][kk] = cvt8(lo, hi);
        }
    }
#pragma unroll
    for (int half = 0; half < 2; ++half) {
        const short* W = Wpk + half * 96 * 512;
        ushort_t* out = half ? pv : h1;
#pragma unroll
        for (int c = 0; c < 8; ++c) {
            const int ct = ct0 + c;
            bf16x8 b[4];
#pragma unroll
            for (int kk = 0; kk < 4; ++kk)
                b[kk] = *(const bf16x8*)(W + ((size_t)(ct * 4 + kk) * 64 + lane) * 8);
            f32x4 acc0 = {0.f, 0.f, 0.f, 0.f}, acc1 = {0.f, 0.f, 0.f, 0.f};
#pragma unroll
            for (int kk = 0; kk < 4; ++kk) {
                acc0 = __builtin_amdgcn_mfma_f32_16x16x32_bf16(a[0][kk], b[kk], acc0, 0, 0, 0);
                acc1 = __builtin_amdgcn_mfma_f32_16x16x32_bf16(a[1][kk], b[kk], acc1, 0, 0, 0);
            }
            const int col = ct * 16 + rlo;
            const float bv = half ? bfcv[col] : 0.f;
#pragma unroll
            for (int r = 0; r < 4; ++r) {
                int row0 = rbase + (lane >> 4) * 4 + r;
                int row1 = row0 + 16;
                if (row0 < nrows) out[(size_t)row0 * 384 + col] = (ushort_t)f2bf(acc0[r] + bv);
                if (row1 < nrows) out[(size_t)row1 * 384 + col] = (ushort_t)f2bf(acc1[r] + bv);
            }
        }
    }
}

// ---------------- generic MFMA GEMM with col-tile blocking (blockIdx.y) -------------------
template<int COLS, int CT_PER, bool BIAS, typename InT, typename OutT>
__global__ __launch_bounds__(256) void mfma_gemm(const InT* __restrict__ in,
        const short* __restrict__ Wpk, const float* __restrict__ bias,
        OutT* __restrict__ out, int nrows) {
    const int lane = threadIdx.x & 63;
    const int wid = threadIdx.x >> 6;
    const int rbase = blockIdx.x * 128 + wid * 32;
    if (rbase >= nrows) return;
    const int ct0 = blockIdx.y * CT_PER;
    const int rlo = lane & 15, khi = (lane >> 4) * 8;
    bf16x8 a[2][4];
#pragma unroll
    for (int t = 0; t < 2; ++t) {
        int row = min(rbase + t * 16 + rlo, nrows - 1);
        const InT* rp = in + (size_t)row * 128 + khi;
#pragma unroll
        for (int kk = 0; kk < 4; ++kk) {
            if constexpr (sizeof(InT) == 4) {
                float4v lo = *(const float4v*)(rp + kk * 32);
                float4v hi = *(const float4v*)(rp + kk * 32 + 4);
                a[t][kk] = cvt8(lo, hi);
            } else {
                a[t][kk] = *(const bf16x8*)(rp + kk * 32);
            }
        }
    }
#pragma unroll
    for (int c = 0; c < CT_PER; ++c) {
        const int ct = ct0 + c;
        bf16x8 b[4];
#pragma unroll
        for (int kk = 0; kk < 4; ++kk)
            b[kk] = *(const bf16x8*)(Wpk + ((size_t)(ct * 4 + kk) * 64 + lane) * 8);
        f32x4 acc0 = {0.f, 0.f, 0.f, 0.f}, acc1 = {0.f, 0.f, 0.f, 0.f};
#pragma unroll
        for (int kk = 0; kk < 4; ++kk) {
            acc0 = __builtin_amdgcn_mfma_f32_16x16x32_bf16(a[0][kk], b[kk], acc0, 0, 0, 0);
            acc1 = __builtin_amdgcn_mfma_f32_16x16x32_bf16(a[1][kk], b[kk], acc1, 0, 0, 0);
        }
        const int col = ct * 16 + rlo;
        const float bv = BIAS ? bias[col] : 0.f;
#pragma unroll
        for (int r = 0; r < 4; ++r) {
            int row0 = rbase + (lane >> 4) * 4 + r;
            int row1 = row0 + 16;
            if constexpr (sizeof(OutT) == 4) {
                if (row0 < nrows) out[(size_t)row0 * COLS + col] = acc0[r] + bv;
                if (row1 < nrows) out[(size_t)row1 * COLS + col] = acc1[r] + bv;
            } else {
                if (row0 < nrows) out[(size_t)row0 * COLS + col] = (OutT)f2bf(acc0[r] + bv);
                if (row1 < nrows) out[(size_t)row1 * COLS + col] = (OutT)f2bf(acc1[r] + bv);
            }
        }
    }
}

// ---------------- vecproj GEMM (all 24 col-tiles, single y): vp12 + v3p bf16 ----------------
__global__ __launch_bounds__(256) void vp_gemm(const float* __restrict__ in,
        const short* __restrict__ Wpk, ushort_t* __restrict__ vp12,
        ushort_t* __restrict__ v3p, int nrows) {
    const int lane = threadIdx.x & 63;
    const int wid = threadIdx.x >> 6;
    const int rbase = blockIdx.x * 128 + wid * 32;
    if (rbase >= nrows) return;
    const int rlo = lane & 15, khi = (lane >> 4) * 8;
    bf16x8 a[2][4];
#pragma unroll
    for (int t = 0; t < 2; ++t) {
        int row = min(rbase + t * 16 + rlo, nrows - 1);
        const float* rp = in + (size_t)row * 128 + khi;
#pragma unroll
        for (int kk = 0; kk < 4; ++kk) {
            float4v lo = *(const float4v*)(rp + kk * 32);
            float4v hi = *(const float4v*)(rp + kk * 32 + 4);
            a[t][kk] = cvt8(lo, hi);
        }
    }
    for (int ct = 0; ct < 24; ++ct) {
        bf16x8 b[4];
#pragma unroll
        for (int kk = 0; kk < 4; ++kk)
            b[kk] = *(const bf16x8*)(Wpk + ((size_t)(ct * 4 + kk) * 64 + lane) * 8);
        f32x4 acc0 = {0.f, 0.f, 0.f, 0.f}, acc1 = {0.f, 0.f, 0.f, 0.f};
#pragma unroll
        for (int kk = 0; kk < 4; ++kk) {
            acc0 = __builtin_amdgcn_mfma_f32_16x16x32_bf16(a[0][kk], b[kk], acc0, 0, 0, 0);
            acc1 = __builtin_amdgcn_mfma_f32_16x16x32_bf16(a[1][kk], b[kk], acc1, 0, 0, 0);
        }
        const int col = ct * 16 + rlo;
#pragma unroll
        for (int r = 0; r < 4; ++r) {
            int row0 = rbase + (lane >> 4) * 4 + r;
            int row1 = row0 + 16;
            if (col < 256) {
                if (row0 < nrows) vp12[(size_t)row0 * 256 + col] = (ushort_t)f2bf(acc0[r]);
                if (row1 < nrows) vp12[(size_t)row1 * 256 + col] = (ushort_t)f2bf(acc1[r]);
            } else {
                if (row0 < nrows) v3p[(size_t)row0 * 128 + col - 256] = (ushort_t)f2bf(acc0[r]);
                if (row1 < nrows) v3p[(size_t)row1 * 128 + col - 256] = (ushort_t)f2bf(acc1[r]);
            }
        }
    }
}

// ---------------- kv stage 1 (bf16 in): per-block partials, no atomics ----------------
__global__ __launch_bounds__(256) void kv_part(const ushort_t* __restrict__ h1,
        const ushort_t* __restrict__ pv, float* __restrict__ slab) {
    __shared__ float kf_s[8][DIM];
    __shared__ float v_s[8][DIM];
    const int tid = threadIdx.x;              // 256
    const int rpb = (NN + KVB - 1) / KVB;     // 59
    const int n0 = blockIdx.x * rpb;
    const int n1 = min(n0 + rpb, NN);
    const int base = tid * 8;
    const int hf = base >> 4;
    const int h = hf >> 4;
    const int d0 = base & 15;
    const int lr = tid >> 5;
    const int lg = tid & 31;
    const bool isK = lg < 16;
    const int le = (lg & 15) * 8;
    float acc[8];
#pragma unroll
    for (int i = 0; i < 8; ++i) acc[i] = 0.f;
    float zacc = 0.f;
    s16x8 praw = {0,0,0,0,0,0,0,0};
    bool pvalid = false;
    {
        int n = n0 + lr;
        pvalid = n < n1;
        if (pvalid) {
            const ushort_t* src = isK ? (h1 + (size_t)n * 384 + 128 + le)
                                      : (pv + (size_t)n * 384 + le);
            praw = *(const s16x8*)src;
        }
    }
    for (int nt = n0; nt < n1; nt += 8) {
        __syncthreads();
        float v8[8];
#pragma unroll
        for (int i = 0; i < 8; ++i) v8[i] = pvalid ? bf2f((unsigned short)praw[i]) : 0.f;
        if (pvalid && isK) {
#pragma unroll
            for (int i = 0; i < 8; ++i) v8[i] = v8[i] > 0.f ? v8[i] + 1.f : expf(v8[i]);
        }
        float* dst = (isK ? kf_s[lr] : v_s[lr]) + le;
#pragma unroll
        for (int i = 0; i < 8; ++i) dst[i] = v8[i];
        __syncthreads();
        {
            int n = nt + 8 + lr;
            pvalid = n < n1;
            if (pvalid) {
                const ushort_t* src = isK ? (h1 + (size_t)n * 384 + 128 + le)
                                          : (pv + (size_t)n * 384 + le);
                praw = *(const s16x8*)src;
            }
        }
#pragma unroll
        for (int r = 0; r < 8; ++r) {
            float kfv = kf_s[r][hf];
#pragma unroll
            for (int i = 0; i < 8; ++i) acc[i] = fmaf(kfv, v_s[r][h * 16 + d0 + i], acc[i]);
            if (tid < 128) zacc += kf_s[r][tid];
        }
    }
    float* row = slab + (size_t)blockIdx.x * 2176;
#pragma unroll
    for (int i = 0; i < 8; ++i) row[base + i] = acc[i];
    if (tid < 128) row[2048 + tid] = zacc;
}

// ---------------- kv stage 2: kvz[i] = sum_b slab[b][i] ----------------
__global__ void kv_final(const float* __restrict__ slab, float* __restrict__ kvz) {
    int i = blockIdx.x * 256 + threadIdx.x;
    if (i >= 2176) return;
    float a[8];
#pragma unroll
    for (int j = 0; j < 8; ++j) a[j] = 0.f;
    for (int b = 0; b < KVB; b += 8) {
#pragma unroll
        for (int j = 0; j < 8; ++j) a[j] += slab[(size_t)(b + j) * 2176 + i];
    }
    kvz[i] = ((a[0] + a[1]) + (a[2] + a[3])) + ((a[4] + a[5]) + (a[6] + a[7]));
}

// ---------------- att(bf16)[n,h*16+d] = (qf . kv) / (qf . z + 1e-6) ----------------
__global__ void attn_apply(const ushort_t* __restrict__ h1, const float* __restrict__ kvz,
                           ushort_t* __restrict__ att) {
    __shared__ float kv_s[8 * 16 * 17];
    __shared__ float z_s[DIM];
    __shared__ float qf_s[8][DIM];
    const int tid = threadIdx.x;              // 128
    const int n0 = blockIdx.x * 8;
    for (int i = tid; i < 2048; i += 128) {
        int hf = i >> 4, d = i & 15;
        kv_s[hf * 17 + d] = kvz[i];
    }
    z_s[tid] = kvz[2048 + tid];
#pragma unroll
    for (int r = 0; r < 8; ++r) {
        float qv = bf2f(h1[(size_t)(n0 + r) * 384 + tid]);
        qf_s[r][tid] = qv > 0.f ? qv + 1.f : expf(qv);
    }
    __syncthreads();
    const int h = tid >> 4, d = tid & 15;
#pragma unroll
    for (int r = 0; r < 8; ++r) {
        float num = 0.f, den = 0.f;
#pragma unroll
        for (int f = 0; f < 16; ++f) {
            float q = qf_s[r][h * 16 + f];
            num = fmaf(q, kv_s[(h * 16 + f) * 17 + d], num);
            den = fmaf(q, z_s[h * 16 + f], den);
        }
        att[(size_t)(n0 + r) * DIM + tid] = (ushort_t)f2bf(num / (den + 1e-6f));
    }
}

// ---------------- vdot(bf16) + P-pack, col-pair vectorized (pv bf16) ----------------
__global__ __launch_bounds__(256) void vecdot_reduce(const ushort_t* __restrict__ vp12,
        const float* __restrict__ vec, const ushort_t* __restrict__ pv,
        ushort_t* __restrict__ vdot, ushort_t* __restrict__ P) {
    const int tid = threadIdx.x;              // 256
    const int c2 = tid & 63;                  // cols {2c2, 2c2+1}
    const int sub = tid >> 6;                 // 0..3
    const int n0 = blockIdx.x * 8;
#pragma unroll
    for (int rr = 0; rr < 2; ++rr) {
        const int n = n0 + sub + rr * 4;
        float a0 = 0.f, a1 = 0.f;
#pragma unroll
        for (int c = 0; c < 3; ++c) {
            unsigned u1 = *(const unsigned*)(vp12 + (size_t)(3 * n + c) * 256 + 2 * c2);
            unsigned u2 = *(const unsigned*)(vp12 + (size_t)(3 * n + c) * 256 + 128 + 2 * c2);
            a0 = fmaf(bf2f((unsigned short)u1), bf2f((unsigned short)u2), a0);
            a1 = fmaf(bf2f((unsigned short)(u1 >> 16)), bf2f((unsigned short)(u2 >> 16)), a1);
        }
        *(unsigned*)(vdot + (size_t)n * 128 + 2 * c2) = pack2(a0, a1);
        unsigned uv1 = *(const unsigned*)(pv + (size_t)n * 384 + 128 + 2 * c2);
        unsigned uv2 = *(const unsigned*)(pv + (size_t)n * 384 + 256 + 2 * c2);
        float v1x = bf2f((unsigned short)uv1), v1y = bf2f((unsigned short)(uv1 >> 16));
        s16x8 pk;
        pk[0] = (short)(ushort_t)(uv2 & 0xffffu);
        pk[4] = (short)(ushort_t)(uv2 >> 16);
#pragma unroll
        for (int c = 0; c < 3; ++c) {
            float2 vc = *(const float2*)(vec + ((size_t)n * 3 + c) * 128 + 2 * c2);
            pk[1 + c] = f2bf(vc.x * v1x);
            pk[5 + c] = f2bf(vc.y * v1y);
        }
        *(s16x8*)(P + (size_t)n * 512 + (size_t)c2 * 8) = pk;
    }
}

// ---------------- edge CSR build ----------------
__global__ void hist_kernel(const int* __restrict__ eidx, int* __restrict__ cnt) {
    int e = blockIdx.x * 256 + threadIdx.x;
    if (e < EE) atomicAdd(&cnt[eidx[EE + e]], 1);
}

__global__ void scan_kernel(const int* __restrict__ cnt, int* __restrict__ off,
                            int* __restrict__ pos) {
    __shared__ int wsum[16];
    const int tid = threadIdx.x;              // 1024
    const int lane = tid & 63, wv = tid >> 6;
    const int PER = 30;
    const int base = tid * PER;
    int local[PER];
    int s = 0;
#pragma unroll
    for (int i = 0; i < PER; ++i) {
        int idx = base + i;
        int c = (idx < NN) ? cnt[idx] : 0;
        local[i] = s;
        s += c;
    }
    int incl = s;
#pragma unroll
    for (int d = 1; d < 64; d <<= 1) {
        int v = __shfl_up(incl, d, 64);
        if (lane >= d) incl += v;
    }
    if (lane == 63) wsum[wv] = incl;
    __syncthreads();
    if (wv == 0 && lane < 16) {
        int v = wsum[lane];
        int iv = v;
#pragma unroll
        for (int d = 1; d < 16; d <<= 1) {
            int u = __shfl_up(iv, d, 16);
            if (lane >= d) iv += u;
        }
        wsum[lane] = iv - v;
    }
    __syncthreads();
    const int carry = wsum[wv] + (incl - s);
#pragma unroll
    for (int i = 0; i < PER; ++i) {
        int idx = base + i;
        if (idx < NN) {
            int v = carry + local[i];
            off[idx] = v;
            pos[idx] = v;
        }
    }
    if (tid == 1023) off[NN] = wsum[15] + incl;
}

// scatter one 16B record per edge: {src, ev0, ev1, ev2}
__global__ void scatter_kernel(const int* __restrict__ eidx, const float* __restrict__ evec,
                               int* __restrict__ pos, int4* __restrict__ sorted4) {
    int e = blockIdx.x * 256 + threadIdx.x;
    if (e >= EE) return;
    int dst = eidx[EE + e];
    int src = eidx[e];
    float e0 = evec[(size_t)e * 3 + 0];
    float e1 = evec[(size_t)e * 3 + 1];
    float e2 = evec[(size_t)e * 3 + 2];
    int p = atomicAdd(&pos[dst], 1);
    sorted4[p] = make_int4(src, __float_as_int(e0), __float_as_int(e1), __float_as_int(e2));
}

// ---------------- segmented gather-reduce: one block (2 groups x 128 lanes) per dst -------
// fully-predicated 8-deep batches (no serial tail).
__global__ __launch_bounds__(256) void edge_agg_kernel(
        const int* __restrict__ off, const int4* __restrict__ sorted4,
        const ushort_t* __restrict__ P, ushort_t* __restrict__ agg) {
    __shared__ int srcs[128];
    __shared__ float evs[3][128];
    __shared__ float part[3][128];
    const int dst = blockIdx.x;
    const int tid = threadIdx.x;              // 256
    const int g = tid >> 7, o = tid & 127;
    const int j0 = off[dst], j1 = off[dst + 1];
    float a0 = 0.f, a1 = 0.f, a2 = 0.f;
    for (int jt = j0; jt < j1; jt += 128) {
        const int m = min(128, j1 - jt);
        if (tid < m) {
            int4 w = sorted4[jt + tid];
            srcs[tid] = w.x;
            evs[0][tid] = __int_as_float(w.y);
            evs[1][tid] = __int_as_float(w.z);
            evs[2][tid] = __int_as_float(w.w);
        }
        __syncthreads();
        for (int jj = g; jj < m; jj += 16) {   // 8 predicated edges per group-iteration
            s16x4 pk[8];
#pragma unroll
            for (int u = 0; u < 8; ++u) {
                int e = min(jj + 2 * u, m - 1);
                pk[u] = *(const s16x4*)(P + (size_t)srcs[e] * 512 + o * 4);
            }
#pragma unroll
            for (int u = 0; u < 8; ++u) {
                int e = jj + 2 * u;
                if (e < m) {
                    float v2 = bf2f((unsigned short)pk[u][0]);
                    a0 += fmaf(evs[0][e], v2, bf2f((unsigned short)pk[u][1]));
                    a1 += fmaf(evs[1][e], v2, bf2f((unsigned short)pk[u][2]));
                    a2 += fmaf(evs[2][e], v2, bf2f((unsigned short)pk[u][3]));
                }
            }
        }
        __syncthreads();
    }
    if (g == 1) { part[0][o] = a0; part[1][o] = a1; part[2][o] = a2; }
    __syncthreads();
    if (g == 0) {
        a0 += part[0][o]; a1 += part[1][o]; a2 += part[2][o];
        agg[((size_t)dst * 3 + 0) * DIM + o] = (ushort_t)f2bf(a0);
        agg[((size_t)dst * 3 + 1) * DIM + o] = (ushort_t)f2bf(a1);
        agg[((size_t)dst * 3 + 2) * DIM + o] = (ushort_t)f2bf(a2);
    }
}

// ---------------- out_x = non_att + ((att + vdot*o2 + o3) @ W_fco + b_fco)*ew (MFMA) ------
__global__ __launch_bounds__(256) void outx_mfma(const ushort_t* __restrict__ att,
        const ushort_t* __restrict__ vdot, const ushort_t* __restrict__ o,
        const short* __restrict__ Wpk, const float* __restrict__ bfco,
        const ushort_t* __restrict__ h1, const float* __restrict__ ew,
        float* __restrict__ outx) {
    const int lane = threadIdx.x & 63;
    const int wid = threadIdx.x >> 6;
    const int rbase = blockIdx.x * 128 + wid * 32;
    if (rbase >= NN) return;
    const int ct0 = blockIdx.y * 4;
    const int rlo = lane & 15, khi = (lane >> 4) * 8;
    bf16x8 a[2][4];
#pragma unroll
    for (int t = 0; t < 2; ++t) {
        int row = min(rbase + t * 16 + rlo, NN - 1);
        const ushort_t* pa = att + (size_t)row * 128 + khi;
        const ushort_t* pd = vdot + (size_t)row * 128 + khi;
        const ushort_t* po = o + (size_t)row * 384 + khi;
#pragma unroll
        for (int kk = 0; kk < 4; ++kk) {
            int kb = kk * 32;
            float4v al, ah, dl, dh, o2l, o2h, o3l, o3h;
            bf8_to_f(*(const bf16x8*)(pa + kb), al, ah);
            bf8_to_f(*(const bf16x8*)(pd + kb), dl, dh);
            bf8_to_f(*(const bf16x8*)(po + 128 + kb), o2l, o2h);
            bf8_to_f(*(const bf16x8*)(po + 256 + kb), o3l, o3h);
            a[t][kk] = cvt8(al + dl * o2l + o3l, ah + dh * o2h + o3h);
        }
    }
    float ewv[2][4];
#pragma unroll
    for (int t = 0; t < 2; ++t)
#pragma unroll
        for (int r = 0; r < 4; ++r)
            ewv[t][r] = ew[min(rbase + t * 16 + (lane >> 4) * 4 + r, NN - 1)];
#pragma unroll
    for (int c = 0; c < 4; ++c) {
        const int ct = ct0 + c;
        bf16x8 b[4];
#pragma unroll
        for (int kk = 0; kk < 4; ++kk)
            b[kk] = *(const bf16x8*)(Wpk + ((size_t)(ct * 4 + kk) * 64 + lane) * 8);
        f32x4 acc0 = {0.f, 0.f, 0.f, 0.f}, acc1 = {0.f, 0.f, 0.f, 0.f};
#pragma unroll
        for (int kk = 0; kk < 4; ++kk) {
            acc0 = __builtin_amdgcn_mfma_f32_16x16x32_bf16(a[0][kk], b[kk], acc0, 0, 0, 0);
            acc1 = __builtin_amdgcn_mfma_f32_16x16x32_bf16(a[1][kk], b[kk], acc1, 0, 0, 0);
        }
        const int col = ct * 16 + rlo;
        const float bv = bfco[col];
#pragma unroll
        for (int r = 0; r < 4; ++r) {
            int row0 = rbase + (lane >> 4) * 4 + r;
            if (row0 < NN)
                outx[(size_t)row0 * 128 + col] =
                    bf2f(h1[(size_t)row0 * 384 + 256 + col]) + (acc0[r] + bv) * ewv[0][r];
            int row1 = row0 + 16;
            if (row1 < NN)
                outx[(size_t)row1 * 128 + col] =
                    bf2f(h1[(size_t)row1 * 384 + 256 + col]) + (acc1[r] + bv) * ewv[1][r];
        }
    }
}

// ---------------- fused: out_vec = LN(v3p*o1 + agg) @ W_equiv  (in-reg LN + MFMA) ---------
__global__ __launch_bounds__(256) void outvec_fused(const ushort_t* __restrict__ v3p,
        const ushort_t* __restrict__ o, const ushort_t* __restrict__ agg,
        const float* __restrict__ ln_scale, const float* __restrict__ ln_bias,
        const short* __restrict__ Wpk, float* __restrict__ outv, int nrows) {
    const int lane = threadIdx.x & 63;
    const int wid = threadIdx.x >> 6;
    const int rbase = blockIdx.x * 128 + wid * 32;
    if (rbase >= nrows) return;
    const int rlo = lane & 15, khi = (lane >> 4) * 8;
    float ls[4][8], lb[4][8];
#pragma unroll
    for (int kk = 0; kk < 4; ++kk)
#pragma unroll
        for (int i = 0; i < 8; ++i) {
            ls[kk][i] = ln_scale[khi + kk * 32 + i];
            lb[kk][i] = ln_bias[khi + kk * 32 + i];
        }
    bf16x8 a[2][4];
#pragma unroll
    for (int t = 0; t < 2; ++t) {
        int row = min(rbase + t * 16 + rlo, nrows - 1);
        int n = row / 3;
        float dv[4][8];
        float s = 0.f, s2 = 0.f;
#pragma unroll
        for (int kk = 0; kk < 4; ++kk) {
            bf16x8 v3 = *(const bf16x8*)(v3p + (size_t)row * 128 + khi + kk * 32);
            bf16x8 oo = *(const bf16x8*)(o + (size_t)n * 384 + khi + kk * 32);
            bf16x8 ag = *(const bf16x8*)(agg + (size_t)row * 128 + khi + kk * 32);
#pragma unroll
            for (int i = 0; i < 8; ++i) {
                float v = fmaf(bf2f((unsigned short)v3[i]), bf2f((unsigned short)oo[i]),
                               bf2f((unsigned short)ag[i]));
                dv[kk][i] = v;
                s += v;
                s2 = fmaf(v, v, s2);
            }
        }
        // row-reduce across the 4 lanes sharing rlo (lane ^ 16, lane ^ 32)
        s += __shfl_xor(s, 16, 64);  s2 += __shfl_xor(s2, 16, 64);
        s += __shfl_xor(s, 32, 64);  s2 += __shfl_xor(s2, 32, 64);
        float mu = s * (1.f / 128.f);
        float rstd = rsqrtf(s2 * (1.f / 128.f) - mu * mu + 1e-5f);
#pragma unroll
        for (int kk = 0; kk < 4; ++kk) {
            bf16x8 r;
#pragma unroll
            for (int i = 0; i < 8; ++i)
                r[i] = f2bf(fmaf((dv[kk][i] - mu) * rstd, ls[kk][i], lb[kk][i]));
            a[t][kk] = r;
        }
    }
#pragma unroll
    for (int ct = 0; ct < 8; ++ct) {
        bf16x8 b[4];
#pragma unroll
        for (int kk = 0; kk < 4; ++kk)
            b[kk] = *(const bf16x8*)(Wpk + ((size_t)(ct * 4 + kk) * 64 + lane) * 8);
        f32x4 acc0 = {0.f, 0.f, 0.f, 0.f}, acc1 = {0.f, 0.f, 0.f, 0.f};
#pragma unroll
        for (int kk = 0; kk < 4; ++kk) {
            acc0 = __builtin_amdgcn_mfma_f32_16x16x32_bf16(a[0][kk], b[kk], acc0, 0, 0, 0);
            acc1 = __builtin_amdgcn_mfma_f32_16x16x32_bf16(a[1][kk], b[kk], acc1, 0, 0, 0);
        }
        const int col = ct * 16 + rlo;
#pragma unroll
        for (int r = 0; r < 4; ++r) {
            int row0 = rbase + (lane >> 4) * 4 + r;
            int row1 = row0 + 16;
            if (row0 < nrows) outv[(size_t)row0 * 128 + col] = acc0[r];
            if (row1 < nrows) outv[(size_t)row1 * 128 + col] = acc1[r];
        }
    }
}

extern "C" void kernel_launch(void* const* d_in, const int* in_sizes, int n_in,
                              void* d_out, int out_size, void* d_ws, size_t ws_size,
                              hipStream_t stream) {
    const float* x          = (const float*)d_in[0];
    const float* vec        = (const float*)d_in[1];
    const float* edge_vec   = (const float*)d_in[2];
    const float* edge_weight= (const float*)d_in[3];
    const float* W_fc1      = (const float*)d_in[4];
    const float* W_fcv      = (const float*)d_in[5];
    const float* b_fcv      = (const float*)d_in[6];
    const float* W_fco      = (const float*)d_in[7];
    const float* b_fco      = (const float*)d_in[8];
    const float* W_out      = (const float*)d_in[9];
    const float* W_vecproj  = (const float*)d_in[10];
    const float* W_equiv    = (const float*)d_in[11];
    const float* ln_scale   = (const float*)d_in[12];
    const float* ln_bias    = (const float*)d_in[13];
    const int*   edge_index = (const int*)d_in[14];

    float* out_x   = (float*)d_out;
    float* out_vec = out_x + (size_t)NN * DIM;
    ushort_t* Pb = (ushort_t*)d_out;           // N x 512 bf16, alias (dead before out writes)

    float* ws   = (float*)d_ws;
    ushort_t* h1_b   = (ushort_t*)ws;                   // N*384 bf16
    ushort_t* pv_b   = h1_b + 11520000;                 // N*384 bf16
    ushort_t* att_b  = pv_b + 11520000;                 // N*128 bf16
    ushort_t* vdot_b = att_b + 3840000;                 // N*128 bf16
    ushort_t* o_b    = vdot_b + 3840000;                // N*384 bf16
    ushort_t* agg_b  = o_b + 11520000;                  // 3N*128 bf16
    ushort_t* v3p_b  = agg_b + 11520000;                // 3N*128 bf16
    float* kvz  = (float*)(v3p_b + 11520000);           // 2176 f32
    // aliases (stream-ordered dead ranges):
    ushort_t* vp12_b = o_b;                             // 3N*256 bf16 spans o_b..agg_b
    float* slab = (float*)o_b;                          // KVB*2176 f32, dead before vp_gemm
    int* cnt    = (int*)(kvz + 2176);                   // N
    int* off    = cnt + NN;                             // N+1
    int* pos    = off + NN + 1;                         // N
    size_t soff = ((size_t)(pos + NN - (int*)ws) + 3) & ~(size_t)3;    // 16B align
    int4* sorted4 = (int4*)((int*)ws + soff);           // E * 16B
    short* Wpk  = (short*)((int*)ws + soff + (size_t)4 * EE);          // 448 frags
    short* pk_fc1  = Wpk;                      // fc1+fcv contiguous (192 frags)
    short* pk_wout = Wpk + 192 * 512;
    short* pk_vp   = Wpk + 288 * 512;          // unified 384-col vecproj (96 frags)
    short* pk_fco  = Wpk + 384 * 512;
    short* pk_weq  = Wpk + 416 * 512;

    hipMemsetAsync(cnt, 0, NN * sizeof(int), stream);

    pack_all<<<112, 256, 0, stream>>>(W_fc1, W_fcv, W_out, W_vecproj, W_fco, W_equiv, Wpk);

    // CSR build (depends only on edge_index / edge_vec)
    hist_kernel<<<(EE + 255) / 256, 256, 0, stream>>>(edge_index, cnt);
    scan_kernel<<<1, 1024, 0, stream>>>(cnt, off, pos);
    scatter_kernel<<<(EE + 255) / 256, 256, 0, stream>>>(edge_index, edge_vec, pos, sorted4);

    const int gN = (NN + 127) / 128;           // 235
    const int g3N = (3 * NN + 127) / 128;      // 704
    x_gemm<<<dim3(gN, 3), 256, 0, stream>>>(x, pk_fc1, b_fcv, h1_b, pv_b, NN);
    kv_part<<<KVB, 256, 0, stream>>>(h1_b, pv_b, slab);
    kv_final<<<9, 256, 0, stream>>>(slab, kvz);
    attn_apply<<<NN / 8, 128, 0, stream>>>(h1_b, kvz, att_b);
    vp_gemm<<<g3N, 256, 0, stream>>>(vec, pk_vp, vp12_b, v3p_b, 3 * NN);
    vecdot_reduce<<<NN / 8, 256, 0, stream>>>(vp12_b, vec, pv_b, vdot_b, Pb);
    mfma_gemm<384, 8, false, ushort_t, ushort_t><<<dim3(gN, 3), 256, 0, stream>>>(att_b, pk_wout, nullptr, o_b, NN);
    edge_agg_kernel<<<NN, 256, 0, stream>>>(off, sorted4, Pb, agg_b);
    outx_mfma<<<dim3(gN, 2), 256, 0, stream>>>(att_b, vdot_b, o_b, pk_fco, b_fco, h1_b, edge_weight, out_x);
    outvec_fused<<<g3N, 256, 0, stream>>>(v3p_b, o_b, agg_b, ln_scale, ln_bias, pk_weq,
                                          out_vec, 3 * NN);
}